// Round 14
// baseline (793.711 us; speedup 1.0000x reference)
//
#include <hip/hip_runtime.h>
#include <hip/hip_bf16.h>
#include <stdint.h>

#define N_NODES 20000
#define N_EDGES 320000
#define DIM 300
#define ADIM 320              // padded activation stride (cols 300..319 = 0)
#define ROWS_PAD 20480        // 160 * 128  (160 row-blocks = 8 XCDs x 20)
#define N_LAYERS 5
#define EDIM 7
#define NGRAPH 128
#define NCLS 6
#define DHALF 150
#define BN_EPS 1e-5f
#define NBUCK 16              // src-tile buckets for msg L2 locality
#define BUCK_W 1250           // nodes per bucket (20000/16)

#define CDIV(a, b) (((a) + (b) - 1) / (b))

typedef short bf16x8 __attribute__((ext_vector_type(8)));
typedef float f32x4 __attribute__((ext_vector_type(4)));
typedef unsigned short ushort_t;

__device__ __forceinline__ float bf2f(ushort_t u) {
    union { float f; uint32_t i; } v; v.i = ((uint32_t)u) << 16; return v.f;
}
__device__ __forceinline__ ushort_t f2bf(float f) {
    union { float f; uint32_t i; } v; v.f = f;
    uint32_t x = v.i;
    x += 0x7FFFu + ((x >> 16) & 1u);   // RTN-even (no inf/nan expected)
    return (ushort_t)(x >> 16);
}

// ---------------- node encoder: h_bf[n][d] = bf16(node_emb[x[n]][d]) --------
__global__ void node_enc_kernel(const int* __restrict__ x,
                                const float* __restrict__ node_emb,
                                ushort_t* __restrict__ h_bf) {
    int idx = blockIdx.x * blockDim.x + threadIdx.x;  // 20000*40
    if (idx >= N_NODES * 40) return;
    int n = idx / 40;
    int d0 = (idx - n * 40) * 8;
    const float* src = node_emb + (size_t)x[n] * DIM;
    union { ushort_t u[8]; uint4 v; } o;
#pragma unroll
    for (int j = 0; j < 8; ++j) {
        int d = d0 + j;
        o.u[j] = (d < DIM) ? f2bf(src[d]) : (ushort_t)0;
    }
    *(uint4*)(h_bf + (size_t)n * ADIM + d0) = o.v;
}

// -------- W transpose+convert: Wt[mat][n][k] = bf16(W[k][n]), k fastest -----
__global__ void wt_prep_kernel(const float* __restrict__ W1,
                               const float* __restrict__ W2,
                               ushort_t* __restrict__ Wt) {
    int idx = blockIdx.x * blockDim.x + threadIdx.x;  // 10*320*320
    if (idx >= 10 * ADIM * ADIM) return;
    int mat = idx / (ADIM * ADIM);
    int rem = idx - mat * ADIM * ADIM;
    int n = rem / ADIM;          // output col (row of Wt)
    int k = rem - n * ADIM;      // k fastest -> coalesced writes
    const float* src = (mat < 5) ? (W1 + (size_t)mat * DIM * DIM)
                                 : (W2 + (size_t)(mat - 5) * DIM * DIM);
    float v = (k < DIM && n < DIM) ? src[(size_t)k * DIM + n] : 0.0f;
    Wt[(size_t)mat * ADIM * ADIM + (size_t)n * ADIM + k] = f2bf(v);
}

// ---------------- CSR build (16-bucket src-tile counting sort) ----------------
// Bucketing each node's edge list by src/1250 makes concurrently-running waves
// gather h-rows from a small moving src-window (~1-2 MB) -> L2-resident.
__global__ void deg16_kernel(const int* __restrict__ src,
                             const int* __restrict__ dst,
                             int* __restrict__ deg16) {
    int e = blockIdx.x * blockDim.x + threadIdx.x;
    if (e < N_EDGES) atomicAdd(&deg16[dst[e] * NBUCK + src[e] / BUCK_W], 1);
}

__global__ void scan16_kernel(const int* __restrict__ deg16,
                              int* __restrict__ off,
                              int* __restrict__ cur16) {
    __shared__ int sh[1024];
    int t = threadIdx.x;
    int base = t * 20;
    int s = 0;
    for (int j = 0; j < 20; ++j) {
        int i = base + j;
        if (i < N_NODES) {
            int tot = 0;
            for (int b = 0; b < NBUCK; ++b) tot += deg16[i * NBUCK + b];
            s += tot;
        }
    }
    sh[t] = s;
    __syncthreads();
    for (int o = 1; o < 1024; o <<= 1) {
        int v = sh[t];
        int add = (t >= o) ? sh[t - o] : 0;
        __syncthreads();
        sh[t] = v + add;
        __syncthreads();
    }
    int run = (t > 0) ? sh[t - 1] : 0;
    for (int j = 0; j < 20; ++j) {
        int i = base + j;
        if (i < N_NODES) {
            off[i] = run;
            int c = run;
            for (int b = 0; b < NBUCK; ++b) {
                cur16[i * NBUCK + b] = c;
                c += deg16[i * NBUCK + b];
            }
            run = c;
        }
    }
    if (t == 1023) off[N_NODES] = sh[1023];
}

__global__ void scatter_kernel(const int* __restrict__ src,
                               const int* __restrict__ dst,
                               const float* __restrict__ edge_attr,
                               int* __restrict__ cur16,
                               int* __restrict__ perm_src,
                               float* __restrict__ pea) {
    int e = blockIdx.x * blockDim.x + threadIdx.x;
    if (e >= N_EDGES) return;
    int s = src[e];
    int d = dst[e];
    int p = atomicAdd(&cur16[d * NBUCK + s / BUCK_W], 1);
    perm_src[p] = s;
    const float* ar = edge_attr + (size_t)e * EDIM;
    float* pr = pea + (size_t)p * 8;
#pragma unroll
    for (int j = 0; j < EDIM; ++j) pr[j] = ar[j];
    pr[7] = 0.0f;
}

// ------- one node per wave, 2-deep pipeline; BNH: h = relu(BN(y_bf)) inline --
// z = (1+eps)*h + sum relu(h[src]+ea)
#define MSG_BLOCKS 5000
template <bool BNH>
__global__ __launch_bounds__(256) void msg_kernel(
    const ushort_t* __restrict__ hsrc, ushort_t* __restrict__ z_bf,
    const int* __restrict__ off, const int* __restrict__ perm_src,
    const float* __restrict__ pea,
    const float* __restrict__ edge_W, const float* __restrict__ edge_b,
    const float* __restrict__ eps, int layer,
    const float* __restrict__ bs1, const float* __restrict__ bs2,
    const float* __restrict__ bg, const float* __restrict__ bbe) {
    int n = (blockIdx.x * 256 + threadIdx.x) >> 6;
    if (n >= N_NODES) return;
    int lane = threadIdx.x & 63;

    float ew[5][7], eb[5], sc[5], sh[5];
#pragma unroll
    for (int c = 0; c < 5; ++c) {
        int d = c * 64 + lane;
        bool ok = (d < DIM);
        eb[c] = ok ? edge_b[d] : 0.0f;
#pragma unroll
        for (int j = 0; j < EDIM; ++j)
            ew[c][j] = ok ? edge_W[j * DIM + d] : 0.0f;
        if (BNH) {
            float s = 0.f, t = 0.f;
            if (ok) {
                const float invn = 1.0f / (float)N_NODES;
                float mean = bs1[d] * invn;
                float var = bs2[d] * invn - mean * mean;
                s = bg[d] * rsqrtf(var + BN_EPS);
                t = bbe[d] - mean * s;
            }
            sc[c] = s;
            sh[c] = t;
        }
    }
    float epsv = 1.0f + eps[layer];

    int p0 = off[n], p1 = off[n + 1];
    float acc[5] = {0.f, 0.f, 0.f, 0.f, 0.f};
    float4 na03, na47;
    float nhv[5];
    int s2i = 0;
    if (p0 < p1) {
        int s1i = perm_src[p0];
        const float* ap = pea + (size_t)p0 * 8;
        na03 = *(const float4*)ap;
        na47 = *(const float4*)(ap + 4);
        const ushort_t* hr = hsrc + (size_t)s1i * ADIM;
#pragma unroll
        for (int c = 0; c < 5; ++c) nhv[c] = bf2f(hr[c * 64 + lane]);
        if (p0 + 1 < p1) s2i = perm_src[p0 + 1];
    }
    for (int p = p0; p < p1; ++p) {
        float4 ca03 = na03, ca47 = na47;
        float chv[5];
#pragma unroll
        for (int c = 0; c < 5; ++c) chv[c] = nhv[c];
        if (p + 1 < p1) {
            const float* ap = pea + (size_t)(p + 1) * 8;
            na03 = *(const float4*)ap;
            na47 = *(const float4*)(ap + 4);
            const ushort_t* hr = hsrc + (size_t)s2i * ADIM;
#pragma unroll
            for (int c = 0; c < 5; ++c) nhv[c] = bf2f(hr[c * 64 + lane]);
            if (p + 2 < p1) s2i = perm_src[p + 2];
        }
#pragma unroll
        for (int c = 0; c < 5; ++c) {
            float hv = BNH ? fmaxf(chv[c] * sc[c] + sh[c], 0.0f) : chv[c];
            float ea = eb[c];
            ea += ca03.x * ew[c][0];
            ea += ca03.y * ew[c][1];
            ea += ca03.z * ew[c][2];
            ea += ca03.w * ew[c][3];
            ea += ca47.x * ew[c][4];
            ea += ca47.y * ew[c][5];
            ea += ca47.z * ew[c][6];
            acc[c] += fmaxf(hv + ea, 0.0f);
        }
    }
    const ushort_t* hn = hsrc + (size_t)n * ADIM;
    ushort_t* zr = z_bf + (size_t)n * ADIM;
#pragma unroll
    for (int c = 0; c < 5; ++c) {
        int d = c * 64 + lane;
        float hv = bf2f(hn[d]);
        if (BNH) hv = fmaxf(hv * sc[c] + sh[c], 0.0f);
        zr[d] = f2bf(epsv * hv + acc[c]);
    }
}

// ---------------- bf16 MFMA GEMM + fused BN stats ----------------------------
// 640 blocks 1D, XCD-clustered: the 4 col-tiles of one 128-row block map to
// consecutive slots on ONE XCD -> A panel fetched into that XCD's L2 once.
// BNA=true: A transformed relu(bf2f(a)*scale[k]+shift[k]) during staging.
// Output bf16 (rows<20000, cols<300); stats from exact f32 accumulators.
__device__ __forceinline__ int swz(int row, int k8) {
    return ((row << 7) + (k8 << 4)) ^ ((row & 7) << 4);
}

template <bool BNA>
__global__ __launch_bounds__(256) void gemm_kernel(
    const ushort_t* __restrict__ A, const ushort_t* __restrict__ Wt,
    ushort_t* __restrict__ Ybf,
    const float* __restrict__ in_s1, const float* __restrict__ in_s2,
    const float* __restrict__ bn_g, const float* __restrict__ bn_be,
    float* __restrict__ gs1, float* __restrict__ gs2) {
    __shared__ ushort_t sA[128 * 64];   // 16 KB, swizzled
    __shared__ ushort_t sB[80 * 64];    // 10 KB, swizzled
    __shared__ float sRed[4 * 160];     // stats cross-wave reduce
    __shared__ float s_scale[ADIM], s_shift[ADIM];
    char* sAc = (char*)sA;
    char* sBc = (char*)sB;

    int tid = threadIdx.x;
    int lane = tid & 63;
    int wv = tid >> 6;                  // wave -> 32-row strip
    int wgid = blockIdx.x;              // 0..639
    int xcd = wgid & 7, slot = wgid >> 3;        // slot 0..79
    int rb = xcd * 20 + (slot >> 2);             // row-block 0..159
    int ct = slot & 3;                           // col-tile 0..3
    int row0 = rb * 128;
    int col0 = ct * 80;
    int l15 = lane & 15, l4 = lane >> 4;

    if (BNA) {
        for (int d = tid; d < ADIM; d += 256) {
            float sc = 0.f, sh = 0.f;
            if (d < DIM) {
                const float invn = 1.0f / (float)N_NODES;
                float mean = in_s1[d] * invn;
                float var = in_s2[d] * invn - mean * mean;
                sc = bn_g[d] * rsqrtf(var + BN_EPS);
                sh = bn_be[d] - mean * sc;
            }
            s_scale[d] = sc;
            s_shift[d] = sh;
        }
        __syncthreads();
    }

    f32x4 acc[2][5];
#pragma unroll
    for (int m = 0; m < 2; ++m)
#pragma unroll
        for (int n = 0; n < 5; ++n) acc[m][n] = (f32x4){0.f, 0.f, 0.f, 0.f};

    for (int kt = 0; kt < 5; ++kt) {
        int k0 = kt * 64;
        // stage A: 128x64 -> 1024 16B chunks, 4/thread
#pragma unroll
        for (int it = 0; it < 4; ++it) {
            int idx = tid + it * 256;
            int row = idx >> 3, k8 = idx & 7;
            const ushort_t* g = A + (size_t)(row0 + row) * ADIM + k0 + k8 * 8;
            uint4 raw = *(const uint4*)g;
            if (!BNA) {
                *(uint4*)(sAc + swz(row, k8)) = raw;
            } else {
                union { ushort_t u[8]; uint4 v; } in, o;
                in.v = raw;
                int kb = k0 + k8 * 8;
#pragma unroll
                for (int j = 0; j < 8; ++j)
                    o.u[j] = f2bf(fmaxf(bf2f(in.u[j]) * s_scale[kb + j] +
                                        s_shift[kb + j], 0.0f));
                *(uint4*)(sAc + swz(row, k8)) = o.v;
            }
        }
        // stage B: 80x64 -> 640 chunks
#pragma unroll
        for (int it = 0; it < 3; ++it) {
            int idx = tid + it * 256;
            if (idx < 640) {
                int row = idx >> 3, k8 = idx & 7;
                const ushort_t* g = Wt + (size_t)(col0 + row) * ADIM + k0 + k8 * 8;
                *(uint4*)(sBc + swz(row, k8)) = *(const uint4*)g;
            }
        }
        __syncthreads();

#pragma unroll
        for (int kk = 0; kk < 2; ++kk) {
            bf16x8 a[2], b[5];
#pragma unroll
            for (int m = 0; m < 2; ++m)
                a[m] = *(const bf16x8*)(sAc + swz(wv * 32 + m * 16 + l15, kk * 4 + l4));
#pragma unroll
            for (int n = 0; n < 5; ++n)
                b[n] = *(const bf16x8*)(sBc + swz(n * 16 + l15, kk * 4 + l4));
#pragma unroll
            for (int m = 0; m < 2; ++m)
#pragma unroll
                for (int n = 0; n < 5; ++n)
                    acc[m][n] = __builtin_amdgcn_mfma_f32_16x16x32_bf16(
                        a[m], b[n], acc[m][n], 0, 0, 0);
        }
        __syncthreads();
    }

    // ---- write bf16 output + per-wave column stats (stats from exact f32) --
#pragma unroll
    for (int n = 0; n < 5; ++n) {
        int col = col0 + n * 16 + l15;
        float s1 = 0.f, s2 = 0.f;
#pragma unroll
        for (int m = 0; m < 2; ++m) {
#pragma unroll
            for (int r = 0; r < 4; ++r) {
                int row = row0 + wv * 32 + m * 16 + l4 * 4 + r;
                float v = acc[m][n][r];
                if (row < N_NODES && col < DIM) {
                    Ybf[(size_t)row * ADIM + col] = f2bf(v);
                    s1 += v;
                    s2 += v * v;
                }
            }
        }
        s1 += __shfl_xor(s1, 16, 64);
        s1 += __shfl_xor(s1, 32, 64);
        s2 += __shfl_xor(s2, 16, 64);
        s2 += __shfl_xor(s2, 32, 64);
        if (l4 == 0) {
            sRed[wv * 160 + n * 16 + l15] = s1;
            sRed[wv * 160 + 80 + n * 16 + l15] = s2;
        }
    }
    __syncthreads();
    if (tid < 160) {
        float v = sRed[tid] + sRed[160 + tid] + sRed[320 + tid] + sRed[480 + tid];
        int cc = (tid < 80) ? tid : tid - 80;
        int col = col0 + cc;
        if (col < DIM) atomicAdd(((tid < 80) ? gs1 : gs2) + col, v);
    }
}

// -------- pooling: sorted batch -> segmented reduction, BN2+relu inline -----
__device__ __forceinline__ int lbound(const int* __restrict__ batch, int g) {
    int lo = 0, hi = N_NODES;
    while (lo < hi) {
        int mid = (lo + hi) >> 1;
        if (batch[mid] < g) lo = mid + 1; else hi = mid;
    }
    return lo;
}

__global__ void pool_kernel(const ushort_t* __restrict__ y_bf,
                            const int* __restrict__ batch,
                            float* __restrict__ pooled,
                            float* __restrict__ counts,
                            const float* __restrict__ bs1,
                            const float* __restrict__ bs2,
                            const float* __restrict__ bg,
                            const float* __restrict__ bbe) {
    int g = blockIdx.x;
    int chunk = blockIdx.y;   // 0..3
    int d = threadIdx.x;      // 320
    int s = lbound(batch, g);
    int e = lbound(batch, g + 1);
    if (chunk == 0 && d == 0) counts[g] = (float)(e - s);
    if (d >= DIM) return;
    const float invn = 1.0f / (float)N_NODES;
    float mean = bs1[d] * invn;
    float var = bs2[d] * invn - mean * mean;
    float sc = bg[d] * rsqrtf(var + BN_EPS);
    float sh = bbe[d] - mean * sc;
    int len = e - s;
    int per = (len + 3) >> 2;
    int r0 = s + chunk * per;
    int r1 = min(r0 + per, e);
    float a = 0.f;
    for (int r = r0; r < r1; ++r)
        a += fmaxf(bf2f(y_bf[(size_t)r * ADIM + d]) * sc + sh, 0.0f);
    if (r1 > r0) atomicAdd(&pooled[(size_t)g * DIM + d], a);
}

// ---------------- MLP head ----------------
__global__ void mlp1_kernel(const float* __restrict__ pooled,
                            const float* __restrict__ counts,
                            const float* __restrict__ Wc1,
                            const float* __restrict__ bc1,
                            float* __restrict__ hidden) {
    int g = blockIdx.x;
    int j = threadIdx.x;  // 192
    if (j >= DHALF) return;
    float inv = 1.0f / fmaxf(counts[g], 1.0f);
    const float* prow = pooled + (size_t)g * DIM;
    float acc = 0.0f;
    for (int k = 0; k < DIM; ++k) acc += prow[k] * Wc1[k * DHALF + j];
    hidden[g * DHALF + j] = fmaxf(acc * inv + bc1[j], 0.0f);
}

__global__ void mlp2_kernel(const float* __restrict__ hidden,
                            const float* __restrict__ Wc2,
                            const float* __restrict__ bc2,
                            float* __restrict__ out) {
    int idx = blockIdx.x * blockDim.x + threadIdx.x;
    if (idx >= NGRAPH * NCLS) return;
    int g = idx / NCLS;
    int c = idx - g * NCLS;
    const float* hrow = hidden + g * DHALF;
    float acc = bc2[c];
    for (int j = 0; j < DHALF; ++j) acc += hrow[j] * Wc2[j * NCLS + c];
    out[idx] = acc;
}

extern "C" void kernel_launch(void* const* d_in, const int* in_sizes, int n_in,
                              void* d_out, int out_size, void* d_ws, size_t ws_size,
                              hipStream_t stream) {
    const int*   x         = (const int*)d_in[0];
    const int*   edge_index= (const int*)d_in[1];
    const float* edge_attr = (const float*)d_in[2];
    const int*   batch     = (const int*)d_in[3];
    const float* node_emb  = (const float*)d_in[4];
    const float* edge_W    = (const float*)d_in[5];
    const float* edge_b    = (const float*)d_in[6];
    const float* eps       = (const float*)d_in[7];
    const float* W1        = (const float*)d_in[8];
    const float* g1        = (const float*)d_in[10];
    const float* be1       = (const float*)d_in[11];
    const float* W2        = (const float*)d_in[12];
    const float* g2        = (const float*)d_in[14];
    const float* be2       = (const float*)d_in[15];
    const float* Wc1       = (const float*)d_in[16];
    const float* bc1       = (const float*)d_in[17];
    const float* Wc2       = (const float*)d_in[18];
    const float* bc2       = (const float*)d_in[19];
    float* out = (float*)d_out;

    const int* src = edge_index;
    const int* dst = edge_index + N_EDGES;

    char* w = (char*)d_ws;
    size_t cur_off = 0;
    auto alloc = [&](size_t bytes) {
        char* p = w + cur_off;
        cur_off += (bytes + 63) & ~(size_t)63;
        return p;
    };
    const size_t AROW = (size_t)ROWS_PAD * ADIM;
    ushort_t* h_bf  = (ushort_t*)alloc(AROW * 2);   // layer-0 input
    ushort_t* zab   = (ushort_t*)alloc(AROW * 2);   // z
    ushort_t* y1bf  = (ushort_t*)alloc(AROW * 2);   // GEMM1 output
    ushort_t* y2bf  = (ushort_t*)alloc(AROW * 2);   // GEMM2 output (pre-BN2)
    ushort_t* Wt    = (ushort_t*)alloc((size_t)10 * ADIM * ADIM * 2);
    int*      deg16 = (int*)alloc((size_t)N_NODES * NBUCK * 4);
    int*      cur16 = (int*)alloc((size_t)N_NODES * NBUCK * 4);
    int*      off   = (int*)alloc((N_NODES + 1) * 4);
    int*      psrc  = (int*)alloc((size_t)N_EDGES * 4);
    float*    pea   = (float*)alloc((size_t)N_EDGES * 8 * 4);
    float*    sbuf  = (float*)alloc((size_t)N_LAYERS * 4 * ADIM * 4); // [L][4][ADIM]
    float*    pooled= (float*)alloc((size_t)NGRAPH * DIM * 4);
    float*    counts= (float*)alloc(NGRAPH * 4);
    float*    hidden= (float*)alloc((size_t)NGRAPH * DHALF * 4);

    auto sa1 = [&](int i) { return sbuf + ((size_t)i * 4 + 0) * ADIM; };
    auto sa2 = [&](int i) { return sbuf + ((size_t)i * 4 + 1) * ADIM; };
    auto sb1 = [&](int i) { return sbuf + ((size_t)i * 4 + 2) * ADIM; };
    auto sb2 = [&](int i) { return sbuf + ((size_t)i * 4 + 3) * ADIM; };

    // ---- prep ----
    hipMemsetAsync(deg16, 0, (size_t)N_NODES * NBUCK * 4, stream);
    hipMemsetAsync(zab + (size_t)N_NODES * ADIM, 0,
                   (size_t)(ROWS_PAD - N_NODES) * ADIM * 2, stream);
    hipMemsetAsync(sbuf, 0, (size_t)N_LAYERS * 4 * ADIM * 4, stream);

    node_enc_kernel<<<CDIV(N_NODES * 40, 256), 256, 0, stream>>>(x, node_emb, h_bf);
    wt_prep_kernel<<<CDIV(10 * ADIM * ADIM, 256), 256, 0, stream>>>(W1, W2, Wt);
    deg16_kernel<<<CDIV(N_EDGES, 256), 256, 0, stream>>>(src, dst, deg16);
    scan16_kernel<<<1, 1024, 0, stream>>>(deg16, off, cur16);
    scatter_kernel<<<CDIV(N_EDGES, 256), 256, 0, stream>>>(src, dst, edge_attr,
                                                           cur16, psrc, pea);

    const int GEMM_BLOCKS = (ROWS_PAD / 128) * 4;  // 640

    for (int i = 0; i < N_LAYERS; ++i) {
        // z = (1+eps)*h + agg, h = relu(BN2(y2_{i-1})) inline for i>0
        if (i == 0)
            msg_kernel<false><<<MSG_BLOCKS, 256, 0, stream>>>(
                h_bf, zab, off, psrc, pea, edge_W, edge_b, eps, i,
                nullptr, nullptr, nullptr, nullptr);
        else
            msg_kernel<true><<<MSG_BLOCKS, 256, 0, stream>>>(
                y2bf, zab, off, psrc, pea, edge_W, edge_b, eps, i,
                sb1(i - 1), sb2(i - 1), g2 + (i - 1) * DIM, be2 + (i - 1) * DIM);
        // y1 = z @ W1, stats -> sa(i)
        gemm_kernel<false><<<GEMM_BLOCKS, 256, 0, stream>>>(
            zab, Wt + (size_t)i * ADIM * ADIM, y1bf,
            nullptr, nullptr, nullptr, nullptr, sa1(i), sa2(i));
        // y2 = relu(BN1(y1)) @ W2 (BN1 fused into staging), stats -> sb(i)
        gemm_kernel<true><<<GEMM_BLOCKS, 256, 0, stream>>>(
            y1bf, Wt + (size_t)(5 + i) * ADIM * ADIM, y2bf,
            sa1(i), sa2(i), g1 + i * DIM, be1 + i * DIM, sb1(i), sb2(i));
    }

    hipMemsetAsync(pooled, 0, (size_t)NGRAPH * DIM * 4, stream);
    dim3 pgrid(NGRAPH, 4);
    pool_kernel<<<pgrid, ADIM, 0, stream>>>(y2bf, batch, pooled, counts,
                                            sb1(N_LAYERS - 1), sb2(N_LAYERS - 1),
                                            g2 + (N_LAYERS - 1) * DIM,
                                            be2 + (N_LAYERS - 1) * DIM);
    mlp1_kernel<<<NGRAPH, 192, 0, stream>>>(pooled, counts, Wc1, bc1, hidden);
    mlp2_kernel<<<CDIV(NGRAPH * NCLS, 256), 256, 0, stream>>>(hidden, Wc2, bc2, out);
}

// Round 15
// 672.719 us; speedup vs baseline: 1.1799x; 1.1799x over previous
//
#include <hip/hip_runtime.h>
#include <hip/hip_bf16.h>
#include <stdint.h>

#define N_NODES 20000
#define N_EDGES 320000
#define DIM 300
#define ADIM 320              // padded activation stride (cols 300..319 = 0)
#define ROWS_PAD 20480        // 160 * 128  (160 row-blocks = 8 XCDs x 20)
#define N_LAYERS 5
#define EDIM 7
#define NGRAPH 128
#define NCLS 6
#define DHALF 150
#define BN_EPS 1e-5f
#define NBUCK 16              // src-tile buckets for msg L2 locality
#define BUCK_W 1250           // nodes per bucket (20000/16)

#define CDIV(a, b) (((a) + (b) - 1) / (b))

typedef short bf16x8 __attribute__((ext_vector_type(8)));
typedef float f32x4 __attribute__((ext_vector_type(4)));
typedef unsigned short ushort_t;

__device__ __forceinline__ float bf2f(ushort_t u) {
    union { float f; uint32_t i; } v; v.i = ((uint32_t)u) << 16; return v.f;
}
__device__ __forceinline__ ushort_t f2bf(float f) {
    union { float f; uint32_t i; } v; v.f = f;
    uint32_t x = v.i;
    x += 0x7FFFu + ((x >> 16) & 1u);   // RTN-even (no inf/nan expected)
    return (ushort_t)(x >> 16);
}

// ---------------- node encoder: h_bf[n][d] = bf16(node_emb[x[n]][d]) --------
__global__ void node_enc_kernel(const int* __restrict__ x,
                                const float* __restrict__ node_emb,
                                ushort_t* __restrict__ h_bf) {
    int idx = blockIdx.x * blockDim.x + threadIdx.x;  // 20000*40
    if (idx >= N_NODES * 40) return;
    int n = idx / 40;
    int d0 = (idx - n * 40) * 8;
    const float* src = node_emb + (size_t)x[n] * DIM;
    union { ushort_t u[8]; uint4 v; } o;
#pragma unroll
    for (int j = 0; j < 8; ++j) {
        int d = d0 + j;
        o.u[j] = (d < DIM) ? f2bf(src[d]) : (ushort_t)0;
    }
    *(uint4*)(h_bf + (size_t)n * ADIM + d0) = o.v;
}

// -------- W transpose+convert: Wt[mat][n][k] = bf16(W[k][n]), k fastest -----
__global__ void wt_prep_kernel(const float* __restrict__ W1,
                               const float* __restrict__ W2,
                               ushort_t* __restrict__ Wt) {
    int idx = blockIdx.x * blockDim.x + threadIdx.x;  // 10*320*320
    if (idx >= 10 * ADIM * ADIM) return;
    int mat = idx / (ADIM * ADIM);
    int rem = idx - mat * ADIM * ADIM;
    int n = rem / ADIM;          // output col (row of Wt)
    int k = rem - n * ADIM;      // k fastest -> coalesced writes
    const float* src = (mat < 5) ? (W1 + (size_t)mat * DIM * DIM)
                                 : (W2 + (size_t)(mat - 5) * DIM * DIM);
    float v = (k < DIM && n < DIM) ? src[(size_t)k * DIM + n] : 0.0f;
    Wt[(size_t)mat * ADIM * ADIM + (size_t)n * ADIM + k] = f2bf(v);
}

// ---------------- CSR build (16-bucket src-tile counting sort) ----------------
__global__ void deg16_kernel(const int* __restrict__ src,
                             const int* __restrict__ dst,
                             int* __restrict__ deg16) {
    int e = blockIdx.x * blockDim.x + threadIdx.x;
    if (e < N_EDGES) atomicAdd(&deg16[dst[e] * NBUCK + src[e] / BUCK_W], 1);
}

__global__ void nodedeg_kernel(const int* __restrict__ deg16,
                               int* __restrict__ nodedeg) {
    int i = blockIdx.x * blockDim.x + threadIdx.x;
    if (i >= N_NODES) return;
    int tot = 0;
#pragma unroll
    for (int b = 0; b < NBUCK; ++b) tot += deg16[i * NBUCK + b];
    nodedeg[i] = tot;
}

__global__ void scan_kernel(const int* __restrict__ nodedeg,
                            int* __restrict__ off) {
    __shared__ int sh[1024];
    int t = threadIdx.x;
    int base = t * 20;
    int local[20];
    int s = 0;
#pragma unroll
    for (int j = 0; j < 20; ++j) {
        int i = base + j;
        int v = (i < N_NODES) ? nodedeg[i] : 0;
        local[j] = v;
        s += v;
    }
    sh[t] = s;
    __syncthreads();
    for (int o = 1; o < 1024; o <<= 1) {
        int v = sh[t];
        int add = (t >= o) ? sh[t - o] : 0;
        __syncthreads();
        sh[t] = v + add;
        __syncthreads();
    }
    int run = (t > 0) ? sh[t - 1] : 0;
#pragma unroll
    for (int j = 0; j < 20; ++j) {
        int i = base + j;
        if (i < N_NODES) {
            off[i] = run;
            run += local[j];
        }
    }
    if (t == 1023) off[N_NODES] = sh[1023];
}

__global__ void cur16_kernel(const int* __restrict__ deg16,
                             const int* __restrict__ off,
                             int* __restrict__ cur16) {
    int i = blockIdx.x * blockDim.x + threadIdx.x;
    if (i >= N_NODES) return;
    int c = off[i];
#pragma unroll
    for (int b = 0; b < NBUCK; ++b) {
        cur16[i * NBUCK + b] = c;
        c += deg16[i * NBUCK + b];
    }
}

__global__ void scatter_kernel(const int* __restrict__ src,
                               const int* __restrict__ dst,
                               const float* __restrict__ edge_attr,
                               int* __restrict__ cur16,
                               int* __restrict__ perm_src,
                               float* __restrict__ pea) {
    int e = blockIdx.x * blockDim.x + threadIdx.x;
    if (e >= N_EDGES) return;
    int s = src[e];
    int d = dst[e];
    int p = atomicAdd(&cur16[d * NBUCK + s / BUCK_W], 1);
    perm_src[p] = s;
    const float* ar = edge_attr + (size_t)e * EDIM;
    float* pr = pea + (size_t)p * 8;
#pragma unroll
    for (int j = 0; j < EDIM; ++j) pr[j] = ar[j];
    pr[7] = 0.0f;
}

// ------- one node per wave, 2-deep pipeline; BNH: h = relu(BN(y_bf)) inline --
// z = (1+eps)*h + sum relu(h[src]+ea)
#define MSG_BLOCKS 5000
template <bool BNH>
__global__ __launch_bounds__(256) void msg_kernel(
    const ushort_t* __restrict__ hsrc, ushort_t* __restrict__ z_bf,
    const int* __restrict__ off, const int* __restrict__ perm_src,
    const float* __restrict__ pea,
    const float* __restrict__ edge_W, const float* __restrict__ edge_b,
    const float* __restrict__ eps, int layer,
    const float* __restrict__ bs1, const float* __restrict__ bs2,
    const float* __restrict__ bg, const float* __restrict__ bbe) {
    int n = (blockIdx.x * 256 + threadIdx.x) >> 6;
    if (n >= N_NODES) return;
    int lane = threadIdx.x & 63;

    float ew[5][7], eb[5], sc[5], sh[5];
#pragma unroll
    for (int c = 0; c < 5; ++c) {
        int d = c * 64 + lane;
        bool ok = (d < DIM);
        eb[c] = ok ? edge_b[d] : 0.0f;
#pragma unroll
        for (int j = 0; j < EDIM; ++j)
            ew[c][j] = ok ? edge_W[j * DIM + d] : 0.0f;
        if (BNH) {
            float s = 0.f, t = 0.f;
            if (ok) {
                const float invn = 1.0f / (float)N_NODES;
                float mean = bs1[d] * invn;
                float var = bs2[d] * invn - mean * mean;
                s = bg[d] * rsqrtf(var + BN_EPS);
                t = bbe[d] - mean * s;
            }
            sc[c] = s;
            sh[c] = t;
        }
    }
    float epsv = 1.0f + eps[layer];

    int p0 = off[n], p1 = off[n + 1];
    float acc[5] = {0.f, 0.f, 0.f, 0.f, 0.f};
    float4 na03, na47;
    float nhv[5];
    int s2i = 0;
    if (p0 < p1) {
        int s1i = perm_src[p0];
        const float* ap = pea + (size_t)p0 * 8;
        na03 = *(const float4*)ap;
        na47 = *(const float4*)(ap + 4);
        const ushort_t* hr = hsrc + (size_t)s1i * ADIM;
#pragma unroll
        for (int c = 0; c < 5; ++c) nhv[c] = bf2f(hr[c * 64 + lane]);
        if (p0 + 1 < p1) s2i = perm_src[p0 + 1];
    }
    for (int p = p0; p < p1; ++p) {
        float4 ca03 = na03, ca47 = na47;
        float chv[5];
#pragma unroll
        for (int c = 0; c < 5; ++c) chv[c] = nhv[c];
        if (p + 1 < p1) {
            const float* ap = pea + (size_t)(p + 1) * 8;
            na03 = *(const float4*)ap;
            na47 = *(const float4*)(ap + 4);
            const ushort_t* hr = hsrc + (size_t)s2i * ADIM;
#pragma unroll
            for (int c = 0; c < 5; ++c) nhv[c] = bf2f(hr[c * 64 + lane]);
            if (p + 2 < p1) s2i = perm_src[p + 2];
        }
#pragma unroll
        for (int c = 0; c < 5; ++c) {
            float hv = BNH ? fmaxf(chv[c] * sc[c] + sh[c], 0.0f) : chv[c];
            float ea = eb[c];
            ea += ca03.x * ew[c][0];
            ea += ca03.y * ew[c][1];
            ea += ca03.z * ew[c][2];
            ea += ca03.w * ew[c][3];
            ea += ca47.x * ew[c][4];
            ea += ca47.y * ew[c][5];
            ea += ca47.z * ew[c][6];
            acc[c] += fmaxf(hv + ea, 0.0f);
        }
    }
    const ushort_t* hn = hsrc + (size_t)n * ADIM;
    ushort_t* zr = z_bf + (size_t)n * ADIM;
#pragma unroll
    for (int c = 0; c < 5; ++c) {
        int d = c * 64 + lane;
        float hv = bf2f(hn[d]);
        if (BNH) hv = fmaxf(hv * sc[c] + sh[c], 0.0f);
        zr[d] = f2bf(epsv * hv + acc[c]);
    }
}

// ---------------- bf16 MFMA GEMM + fused BN stats ----------------------------
// 640 blocks 1D, XCD-clustered: the 4 col-tiles of one 128-row block map to
// consecutive slots on ONE XCD -> A panel fetched into that XCD's L2 once.
// BNA=true: A transformed relu(bf2f(a)*scale[k]+shift[k]) during staging.
// Output bf16 (rows<20000, cols<300); stats from exact f32 accumulators.
__device__ __forceinline__ int swz(int row, int k8) {
    return ((row << 7) + (k8 << 4)) ^ ((row & 7) << 4);
}

template <bool BNA>
__global__ __launch_bounds__(256) void gemm_kernel(
    const ushort_t* __restrict__ A, const ushort_t* __restrict__ Wt,
    ushort_t* __restrict__ Ybf,
    const float* __restrict__ in_s1, const float* __restrict__ in_s2,
    const float* __restrict__ bn_g, const float* __restrict__ bn_be,
    float* __restrict__ gs1, float* __restrict__ gs2) {
    __shared__ ushort_t sA[128 * 64];   // 16 KB, swizzled
    __shared__ ushort_t sB[80 * 64];    // 10 KB, swizzled
    __shared__ float sRed[4 * 160];     // stats cross-wave reduce
    __shared__ float s_scale[ADIM], s_shift[ADIM];
    char* sAc = (char*)sA;
    char* sBc = (char*)sB;

    int tid = threadIdx.x;
    int lane = tid & 63;
    int wv = tid >> 6;                  // wave -> 32-row strip
    int wgid = blockIdx.x;              // 0..639
    int xcd = wgid & 7, slot = wgid >> 3;        // slot 0..79
    int rb = xcd * 20 + (slot >> 2);             // row-block 0..159
    int ct = slot & 3;                           // col-tile 0..3
    int row0 = rb * 128;
    int col0 = ct * 80;
    int l15 = lane & 15, l4 = lane >> 4;

    if (BNA) {
        for (int d = tid; d < ADIM; d += 256) {
            float sc = 0.f, sh = 0.f;
            if (d < DIM) {
                const float invn = 1.0f / (float)N_NODES;
                float mean = in_s1[d] * invn;
                float var = in_s2[d] * invn - mean * mean;
                sc = bn_g[d] * rsqrtf(var + BN_EPS);
                sh = bn_be[d] - mean * sc;
            }
            s_scale[d] = sc;
            s_shift[d] = sh;
        }
        __syncthreads();
    }

    f32x4 acc[2][5];
#pragma unroll
    for (int m = 0; m < 2; ++m)
#pragma unroll
        for (int n = 0; n < 5; ++n) acc[m][n] = (f32x4){0.f, 0.f, 0.f, 0.f};

    for (int kt = 0; kt < 5; ++kt) {
        int k0 = kt * 64;
        // stage A: 128x64 -> 1024 16B chunks, 4/thread
#pragma unroll
        for (int it = 0; it < 4; ++it) {
            int idx = tid + it * 256;
            int row = idx >> 3, k8 = idx & 7;
            const ushort_t* g = A + (size_t)(row0 + row) * ADIM + k0 + k8 * 8;
            uint4 raw = *(const uint4*)g;
            if (!BNA) {
                *(uint4*)(sAc + swz(row, k8)) = raw;
            } else {
                union { ushort_t u[8]; uint4 v; } in, o;
                in.v = raw;
                int kb = k0 + k8 * 8;
#pragma unroll
                for (int j = 0; j < 8; ++j)
                    o.u[j] = f2bf(fmaxf(bf2f(in.u[j]) * s_scale[kb + j] +
                                        s_shift[kb + j], 0.0f));
                *(uint4*)(sAc + swz(row, k8)) = o.v;
            }
        }
        // stage B: 80x64 -> 640 chunks
#pragma unroll
        for (int it = 0; it < 3; ++it) {
            int idx = tid + it * 256;
            if (idx < 640) {
                int row = idx >> 3, k8 = idx & 7;
                const ushort_t* g = Wt + (size_t)(col0 + row) * ADIM + k0 + k8 * 8;
                *(uint4*)(sBc + swz(row, k8)) = *(const uint4*)g;
            }
        }
        __syncthreads();

#pragma unroll
        for (int kk = 0; kk < 2; ++kk) {
            bf16x8 a[2], b[5];
#pragma unroll
            for (int m = 0; m < 2; ++m)
                a[m] = *(const bf16x8*)(sAc + swz(wv * 32 + m * 16 + l15, kk * 4 + l4));
#pragma unroll
            for (int n = 0; n < 5; ++n)
                b[n] = *(const bf16x8*)(sBc + swz(n * 16 + l15, kk * 4 + l4));
#pragma unroll
            for (int m = 0; m < 2; ++m)
#pragma unroll
                for (int n = 0; n < 5; ++n)
                    acc[m][n] = __builtin_amdgcn_mfma_f32_16x16x32_bf16(
                        a[m], b[n], acc[m][n], 0, 0, 0);
        }
        __syncthreads();
    }

    // ---- write bf16 output + per-wave column stats (stats from exact f32) --
#pragma unroll
    for (int n = 0; n < 5; ++n) {
        int col = col0 + n * 16 + l15;
        float s1 = 0.f, s2 = 0.f;
#pragma unroll
        for (int m = 0; m < 2; ++m) {
#pragma unroll
            for (int r = 0; r < 4; ++r) {
                int row = row0 + wv * 32 + m * 16 + l4 * 4 + r;
                float v = acc[m][n][r];
                if (row < N_NODES && col < DIM) {
                    Ybf[(size_t)row * ADIM + col] = f2bf(v);
                    s1 += v;
                    s2 += v * v;
                }
            }
        }
        s1 += __shfl_xor(s1, 16, 64);
        s1 += __shfl_xor(s1, 32, 64);
        s2 += __shfl_xor(s2, 16, 64);
        s2 += __shfl_xor(s2, 32, 64);
        if (l4 == 0) {
            sRed[wv * 160 + n * 16 + l15] = s1;
            sRed[wv * 160 + 80 + n * 16 + l15] = s2;
        }
    }
    __syncthreads();
    if (tid < 160) {
        float v = sRed[tid] + sRed[160 + tid] + sRed[320 + tid] + sRed[480 + tid];
        int cc = (tid < 80) ? tid : tid - 80;
        int col = col0 + cc;
        if (col < DIM) atomicAdd(((tid < 80) ? gs1 : gs2) + col, v);
    }
}

// -------- pooling: sorted batch -> segmented reduction, BN2+relu inline -----
__device__ __forceinline__ int lbound(const int* __restrict__ batch, int g) {
    int lo = 0, hi = N_NODES;
    while (lo < hi) {
        int mid = (lo + hi) >> 1;
        if (batch[mid] < g) lo = mid + 1; else hi = mid;
    }
    return lo;
}

__global__ void pool_kernel(const ushort_t* __restrict__ y_bf,
                            const int* __restrict__ batch,
                            float* __restrict__ pooled,
                            float* __restrict__ counts,
                            const float* __restrict__ bs1,
                            const float* __restrict__ bs2,
                            const float* __restrict__ bg,
                            const float* __restrict__ bbe) {
    int g = blockIdx.x;
    int chunk = blockIdx.y;   // 0..3
    int d = threadIdx.x;      // 320
    int s = lbound(batch, g);
    int e = lbound(batch, g + 1);
    if (chunk == 0 && d == 0) counts[g] = (float)(e - s);
    if (d >= DIM) return;
    const float invn = 1.0f / (float)N_NODES;
    float mean = bs1[d] * invn;
    float var = bs2[d] * invn - mean * mean;
    float sc = bg[d] * rsqrtf(var + BN_EPS);
    float sh = bbe[d] - mean * sc;
    int len = e - s;
    int per = (len + 3) >> 2;
    int r0 = s + chunk * per;
    int r1 = min(r0 + per, e);
    float a = 0.f;
    for (int r = r0; r < r1; ++r)
        a += fmaxf(bf2f(y_bf[(size_t)r * ADIM + d]) * sc + sh, 0.0f);
    if (r1 > r0) atomicAdd(&pooled[(size_t)g * DIM + d], a);
}

// ---------------- MLP head ----------------
__global__ void mlp1_kernel(const float* __restrict__ pooled,
                            const float* __restrict__ counts,
                            const float* __restrict__ Wc1,
                            const float* __restrict__ bc1,
                            float* __restrict__ hidden) {
    int g = blockIdx.x;
    int j = threadIdx.x;  // 192
    if (j >= DHALF) return;
    float inv = 1.0f / fmaxf(counts[g], 1.0f);
    const float* prow = pooled + (size_t)g * DIM;
    float acc = 0.0f;
    for (int k = 0; k < DIM; ++k) acc += prow[k] * Wc1[k * DHALF + j];
    hidden[g * DHALF + j] = fmaxf(acc * inv + bc1[j], 0.0f);
}

__global__ void mlp2_kernel(const float* __restrict__ hidden,
                            const float* __restrict__ Wc2,
                            const float* __restrict__ bc2,
                            float* __restrict__ out) {
    int idx = blockIdx.x * blockDim.x + threadIdx.x;
    if (idx >= NGRAPH * NCLS) return;
    int g = idx / NCLS;
    int c = idx - g * NCLS;
    const float* hrow = hidden + g * DHALF;
    float acc = bc2[c];
    for (int j = 0; j < DHALF; ++j) acc += hrow[j] * Wc2[j * NCLS + c];
    out[idx] = acc;
}

extern "C" void kernel_launch(void* const* d_in, const int* in_sizes, int n_in,
                              void* d_out, int out_size, void* d_ws, size_t ws_size,
                              hipStream_t stream) {
    const int*   x         = (const int*)d_in[0];
    const int*   edge_index= (const int*)d_in[1];
    const float* edge_attr = (const float*)d_in[2];
    const int*   batch     = (const int*)d_in[3];
    const float* node_emb  = (const float*)d_in[4];
    const float* edge_W    = (const float*)d_in[5];
    const float* edge_b    = (const float*)d_in[6];
    const float* eps       = (const float*)d_in[7];
    const float* W1        = (const float*)d_in[8];
    const float* g1        = (const float*)d_in[10];
    const float* be1       = (const float*)d_in[11];
    const float* W2        = (const float*)d_in[12];
    const float* g2        = (const float*)d_in[14];
    const float* be2       = (const float*)d_in[15];
    const float* Wc1       = (const float*)d_in[16];
    const float* bc1       = (const float*)d_in[17];
    const float* Wc2       = (const float*)d_in[18];
    const float* bc2       = (const float*)d_in[19];
    float* out = (float*)d_out;

    const int* src = edge_index;
    const int* dst = edge_index + N_EDGES;

    char* w = (char*)d_ws;
    size_t cur_off = 0;
    auto alloc = [&](size_t bytes) {
        char* p = w + cur_off;
        cur_off += (bytes + 63) & ~(size_t)63;
        return p;
    };
    const size_t AROW = (size_t)ROWS_PAD * ADIM;
    ushort_t* h_bf  = (ushort_t*)alloc(AROW * 2);   // layer-0 input
    ushort_t* zab   = (ushort_t*)alloc(AROW * 2);   // z
    ushort_t* y1bf  = (ushort_t*)alloc(AROW * 2);   // GEMM1 output
    ushort_t* y2bf  = (ushort_t*)alloc(AROW * 2);   // GEMM2 output (pre-BN2)
    ushort_t* Wt    = (ushort_t*)alloc((size_t)10 * ADIM * ADIM * 2);
    int*      deg16 = (int*)alloc((size_t)N_NODES * NBUCK * 4);
    int*      cur16 = (int*)alloc((size_t)N_NODES * NBUCK * 4);
    int*      nodedeg = (int*)alloc((size_t)N_NODES * 4);
    int*      off   = (int*)alloc((N_NODES + 1) * 4);
    int*      psrc  = (int*)alloc((size_t)N_EDGES * 4);
    float*    pea   = (float*)alloc((size_t)N_EDGES * 8 * 4);
    float*    sbuf  = (float*)alloc((size_t)N_LAYERS * 4 * ADIM * 4); // [L][4][ADIM]
    float*    pooled= (float*)alloc((size_t)NGRAPH * DIM * 4);
    float*    counts= (float*)alloc(NGRAPH * 4);
    float*    hidden= (float*)alloc((size_t)NGRAPH * DHALF * 4);

    auto sa1 = [&](int i) { return sbuf + ((size_t)i * 4 + 0) * ADIM; };
    auto sa2 = [&](int i) { return sbuf + ((size_t)i * 4 + 1) * ADIM; };
    auto sb1 = [&](int i) { return sbuf + ((size_t)i * 4 + 2) * ADIM; };
    auto sb2 = [&](int i) { return sbuf + ((size_t)i * 4 + 3) * ADIM; };

    // ---- prep ----
    hipMemsetAsync(deg16, 0, (size_t)N_NODES * NBUCK * 4, stream);
    hipMemsetAsync(zab + (size_t)N_NODES * ADIM, 0,
                   (size_t)(ROWS_PAD - N_NODES) * ADIM * 2, stream);
    hipMemsetAsync(sbuf, 0, (size_t)N_LAYERS * 4 * ADIM * 4, stream);

    node_enc_kernel<<<CDIV(N_NODES * 40, 256), 256, 0, stream>>>(x, node_emb, h_bf);
    wt_prep_kernel<<<CDIV(10 * ADIM * ADIM, 256), 256, 0, stream>>>(W1, W2, Wt);
    deg16_kernel<<<CDIV(N_EDGES, 256), 256, 0, stream>>>(src, dst, deg16);
    nodedeg_kernel<<<CDIV(N_NODES, 256), 256, 0, stream>>>(deg16, nodedeg);
    scan_kernel<<<1, 1024, 0, stream>>>(nodedeg, off);
    cur16_kernel<<<CDIV(N_NODES, 256), 256, 0, stream>>>(deg16, off, cur16);
    scatter_kernel<<<CDIV(N_EDGES, 256), 256, 0, stream>>>(src, dst, edge_attr,
                                                           cur16, psrc, pea);

    const int GEMM_BLOCKS = (ROWS_PAD / 128) * 4;  // 640

    for (int i = 0; i < N_LAYERS; ++i) {
        // z = (1+eps)*h + agg, h = relu(BN2(y2_{i-1})) inline for i>0
        if (i == 0)
            msg_kernel<false><<<MSG_BLOCKS, 256, 0, stream>>>(
                h_bf, zab, off, psrc, pea, edge_W, edge_b, eps, i,
                nullptr, nullptr, nullptr, nullptr);
        else
            msg_kernel<true><<<MSG_BLOCKS, 256, 0, stream>>>(
                y2bf, zab, off, psrc, pea, edge_W, edge_b, eps, i,
                sb1(i - 1), sb2(i - 1), g2 + (i - 1) * DIM, be2 + (i - 1) * DIM);
        // y1 = z @ W1, stats -> sa(i)
        gemm_kernel<false><<<GEMM_BLOCKS, 256, 0, stream>>>(
            zab, Wt + (size_t)i * ADIM * ADIM, y1bf,
            nullptr, nullptr, nullptr, nullptr, sa1(i), sa2(i));
        // y2 = relu(BN1(y1)) @ W2 (BN1 fused into staging), stats -> sb(i)
        gemm_kernel<true><<<GEMM_BLOCKS, 256, 0, stream>>>(
            y1bf, Wt + (size_t)(5 + i) * ADIM * ADIM, y2bf,
            sa1(i), sa2(i), g1 + i * DIM, be1 + i * DIM, sb1(i), sb2(i));
    }

    hipMemsetAsync(pooled, 0, (size_t)NGRAPH * DIM * 4, stream);
    dim3 pgrid(NGRAPH, 4);
    pool_kernel<<<pgrid, ADIM, 0, stream>>>(y2bf, batch, pooled, counts,
                                            sb1(N_LAYERS - 1), sb2(N_LAYERS - 1),
                                            g2 + (N_LAYERS - 1) * DIM,
                                            be2 + (N_LAYERS - 1) * DIM);
    mlp1_kernel<<<NGRAPH, 192, 0, stream>>>(pooled, counts, Wc1, bc1, hidden);
    mlp2_kernel<<<CDIV(NGRAPH * NCLS, 256), 256, 0, stream>>>(hidden, Wc2, bc2, out);
}

// Round 16
// 650.823 us; speedup vs baseline: 1.2195x; 1.0336x over previous
//
#include <hip/hip_runtime.h>
#include <hip/hip_bf16.h>
#include <stdint.h>

#define N_NODES 20000
#define N_EDGES 320000
#define DIM 300
#define ADIM 320              // padded activation stride (cols 300..319 = 0)
#define ROWS_PAD 20480        // 160 * 128  (160 row-blocks = 8 XCDs x 20)
#define N_LAYERS 5
#define EDIM 7
#define NGRAPH 128
#define NCLS 6
#define DHALF 150
#define BN_EPS 1e-5f
#define NBUCK 16
#define BUCK_W 1250

#define CDIV(a, b) (((a) + (b) - 1) / (b))

typedef short bf16x8 __attribute__((ext_vector_type(8)));
typedef float f32x4 __attribute__((ext_vector_type(4)));
typedef unsigned short ushort_t;

__device__ __forceinline__ float bf2f(ushort_t u) {
    union { float f; uint32_t i; } v; v.i = ((uint32_t)u) << 16; return v.f;
}
__device__ __forceinline__ ushort_t f2bf(float f) {
    union { float f; uint32_t i; } v; v.f = f;
    uint32_t x = v.i;
    x += 0x7FFFu + ((x >> 16) & 1u);   // RTN-even (no inf/nan expected)
    return (ushort_t)(x >> 16);
}

// async global->LDS, 16B per lane; LDS dest = uniform base + lane*16
__device__ __forceinline__ void gload_lds16(const void* g, void* l) {
    __builtin_amdgcn_global_load_lds(
        (const __attribute__((address_space(1))) uint32_t*)g,
        (__attribute__((address_space(3))) uint32_t*)l, 16, 0, 0);
}

// ---------------- node encoder: h_bf[n][d] = bf16(node_emb[x[n]][d]) --------
__global__ void node_enc_kernel(const int* __restrict__ x,
                                const float* __restrict__ node_emb,
                                ushort_t* __restrict__ h_bf) {
    int idx = blockIdx.x * blockDim.x + threadIdx.x;  // 20000*40
    if (idx >= N_NODES * 40) return;
    int n = idx / 40;
    int d0 = (idx - n * 40) * 8;
    const float* src = node_emb + (size_t)x[n] * DIM;
    union { ushort_t u[8]; uint4 v; } o;
#pragma unroll
    for (int j = 0; j < 8; ++j) {
        int d = d0 + j;
        o.u[j] = (d < DIM) ? f2bf(src[d]) : (ushort_t)0;
    }
    *(uint4*)(h_bf + (size_t)n * ADIM + d0) = o.v;
}

// -------- W transpose+convert: Wt[mat][n][k] = bf16(W[k][n]), k fastest -----
__global__ void wt_prep_kernel(const float* __restrict__ W1,
                               const float* __restrict__ W2,
                               ushort_t* __restrict__ Wt) {
    int idx = blockIdx.x * blockDim.x + threadIdx.x;  // 10*320*320
    if (idx >= 10 * ADIM * ADIM) return;
    int mat = idx / (ADIM * ADIM);
    int rem = idx - mat * ADIM * ADIM;
    int n = rem / ADIM;
    int k = rem - n * ADIM;
    const float* src = (mat < 5) ? (W1 + (size_t)mat * DIM * DIM)
                                 : (W2 + (size_t)(mat - 5) * DIM * DIM);
    float v = (k < DIM && n < DIM) ? src[(size_t)k * DIM + n] : 0.0f;
    Wt[(size_t)mat * ADIM * ADIM + (size_t)n * ADIM + k] = f2bf(v);
}

// ---------------- CSR build (16-bucket src-tile counting sort) ----------------
__global__ void deg16_kernel(const int* __restrict__ src,
                             const int* __restrict__ dst,
                             int* __restrict__ deg16) {
    int e = blockIdx.x * blockDim.x + threadIdx.x;
    if (e < N_EDGES) atomicAdd(&deg16[dst[e] * NBUCK + src[e] / BUCK_W], 1);
}

__global__ void nodedeg_kernel(const int* __restrict__ deg16,
                               int* __restrict__ nodedeg) {
    int i = blockIdx.x * blockDim.x + threadIdx.x;
    if (i >= N_NODES) return;
    int tot = 0;
#pragma unroll
    for (int b = 0; b < NBUCK; ++b) tot += deg16[i * NBUCK + b];
    nodedeg[i] = tot;
}

__global__ void scan_kernel(const int* __restrict__ nodedeg,
                            int* __restrict__ off) {
    __shared__ int sh[1024];
    int t = threadIdx.x;
    int base = t * 20;
    int local[20];
    int s = 0;
#pragma unroll
    for (int j = 0; j < 20; ++j) {
        int i = base + j;
        int v = (i < N_NODES) ? nodedeg[i] : 0;
        local[j] = v;
        s += v;
    }
    sh[t] = s;
    __syncthreads();
    for (int o = 1; o < 1024; o <<= 1) {
        int v = sh[t];
        int add = (t >= o) ? sh[t - o] : 0;
        __syncthreads();
        sh[t] = v + add;
        __syncthreads();
    }
    int run = (t > 0) ? sh[t - 1] : 0;
#pragma unroll
    for (int j = 0; j < 20; ++j) {
        int i = base + j;
        if (i < N_NODES) {
            off[i] = run;
            run += local[j];
        }
    }
    if (t == 1023) off[N_NODES] = sh[1023];
}

__global__ void cur16_kernel(const int* __restrict__ deg16,
                             const int* __restrict__ off,
                             int* __restrict__ cur16) {
    int i = blockIdx.x * blockDim.x + threadIdx.x;
    if (i >= N_NODES) return;
    int c = off[i];
#pragma unroll
    for (int b = 0; b < NBUCK; ++b) {
        cur16[i * NBUCK + b] = c;
        c += deg16[i * NBUCK + b];
    }
}

__global__ void scatter_kernel(const int* __restrict__ src,
                               const int* __restrict__ dst,
                               const float* __restrict__ edge_attr,
                               int* __restrict__ cur16,
                               int* __restrict__ perm_src,
                               float* __restrict__ pea) {
    int e = blockIdx.x * blockDim.x + threadIdx.x;
    if (e >= N_EDGES) return;
    int s = src[e];
    int d = dst[e];
    int p = atomicAdd(&cur16[d * NBUCK + s / BUCK_W], 1);
    perm_src[p] = s;
    const float* ar = edge_attr + (size_t)e * EDIM;
    float* pr = pea + (size_t)p * 8;
#pragma unroll
    for (int j = 0; j < EDIM; ++j) pr[j] = ar[j];
    pr[7] = 0.0f;
}

// ------- one node per wave, 2-deep pipeline; BNH: h = relu(BN(y_bf)) inline --
// z = (1+eps)*h + sum relu(h[src]+ea)
#define MSG_BLOCKS 5000
template <bool BNH>
__global__ __launch_bounds__(256) void msg_kernel(
    const ushort_t* __restrict__ hsrc, ushort_t* __restrict__ z_bf,
    const int* __restrict__ off, const int* __restrict__ perm_src,
    const float* __restrict__ pea,
    const float* __restrict__ edge_W, const float* __restrict__ edge_b,
    const float* __restrict__ eps, int layer,
    const float* __restrict__ bs1, const float* __restrict__ bs2,
    const float* __restrict__ bg, const float* __restrict__ bbe) {
    int n = (blockIdx.x * 256 + threadIdx.x) >> 6;
    if (n >= N_NODES) return;
    int lane = threadIdx.x & 63;

    float ew[5][7], eb[5], sc[5], sh[5];
#pragma unroll
    for (int c = 0; c < 5; ++c) {
        int d = c * 64 + lane;
        bool ok = (d < DIM);
        eb[c] = ok ? edge_b[d] : 0.0f;
#pragma unroll
        for (int j = 0; j < EDIM; ++j)
            ew[c][j] = ok ? edge_W[j * DIM + d] : 0.0f;
        if (BNH) {
            float s = 0.f, t = 0.f;
            if (ok) {
                const float invn = 1.0f / (float)N_NODES;
                float mean = bs1[d] * invn;
                float var = bs2[d] * invn - mean * mean;
                s = bg[d] * rsqrtf(var + BN_EPS);
                t = bbe[d] - mean * s;
            }
            sc[c] = s;
            sh[c] = t;
        }
    }
    float epsv = 1.0f + eps[layer];

    int p0 = off[n], p1 = off[n + 1];
    float acc[5] = {0.f, 0.f, 0.f, 0.f, 0.f};
    float4 na03, na47;
    float nhv[5];
    int s2i = 0;
    if (p0 < p1) {
        int s1i = perm_src[p0];
        const float* ap = pea + (size_t)p0 * 8;
        na03 = *(const float4*)ap;
        na47 = *(const float4*)(ap + 4);
        const ushort_t* hr = hsrc + (size_t)s1i * ADIM;
#pragma unroll
        for (int c = 0; c < 5; ++c) nhv[c] = bf2f(hr[c * 64 + lane]);
        if (p0 + 1 < p1) s2i = perm_src[p0 + 1];
    }
    for (int p = p0; p < p1; ++p) {
        float4 ca03 = na03, ca47 = na47;
        float chv[5];
#pragma unroll
        for (int c = 0; c < 5; ++c) chv[c] = nhv[c];
        if (p + 1 < p1) {
            const float* ap = pea + (size_t)(p + 1) * 8;
            na03 = *(const float4*)ap;
            na47 = *(const float4*)(ap + 4);
            const ushort_t* hr = hsrc + (size_t)s2i * ADIM;
#pragma unroll
            for (int c = 0; c < 5; ++c) nhv[c] = bf2f(hr[c * 64 + lane]);
            if (p + 2 < p1) s2i = perm_src[p + 2];
        }
#pragma unroll
        for (int c = 0; c < 5; ++c) {
            float hv = BNH ? fmaxf(chv[c] * sc[c] + sh[c], 0.0f) : chv[c];
            float ea = eb[c];
            ea += ca03.x * ew[c][0];
            ea += ca03.y * ew[c][1];
            ea += ca03.z * ew[c][2];
            ea += ca03.w * ew[c][3];
            ea += ca47.x * ew[c][4];
            ea += ca47.y * ew[c][5];
            ea += ca47.z * ew[c][6];
            acc[c] += fmaxf(hv + ea, 0.0f);
        }
    }
    const ushort_t* hn = hsrc + (size_t)n * ADIM;
    ushort_t* zr = z_bf + (size_t)n * ADIM;
#pragma unroll
    for (int c = 0; c < 5; ++c) {
        int d = c * 64 + lane;
        float hv = bf2f(hn[d]);
        if (BNH) hv = fmaxf(hv * sc[c] + sh[c], 0.0f);
        zr[d] = f2bf(epsv * hv + acc[c]);
    }
}

// ---------------- bf16 MFMA GEMM + fused BN stats ----------------------------
// 640 blocks 1D, XCD-clustered. Staging via global_load_lds (rule #21):
// linear LDS dest + inverse-swizzled global source (k8 ^ (row&7), static
// per-lane since row&7 == lane>>3 within each 1KB chunk) + swizzled read.
// BNA=true: A transformed relu(bf2f(a)*scale+shift) during reg-staging
// (transform prevents gload_lds for A); B still async.
// Output bf16 (rows<20000, cols<300); stats from exact f32 accumulators.
__device__ __forceinline__ int swz(int row, int k8) {
    return ((row << 7) + (k8 << 4)) ^ ((row & 7) << 4);
}

template <bool BNA>
__global__ __launch_bounds__(256) void gemm_kernel(
    const ushort_t* __restrict__ A, const ushort_t* __restrict__ Wt,
    ushort_t* __restrict__ Ybf,
    const float* __restrict__ in_s1, const float* __restrict__ in_s2,
    const float* __restrict__ bn_g, const float* __restrict__ bn_be,
    float* __restrict__ gs1, float* __restrict__ gs2) {
    __shared__ ushort_t sA[128 * 64];   // 16 KB (16 chunks of 1KB)
    __shared__ ushort_t sB[80 * 64];    // 10 KB (10 chunks)
    __shared__ float sRed[4 * 160];
    __shared__ float s_scale[ADIM], s_shift[ADIM];
    char* sAc = (char*)sA;
    char* sBc = (char*)sB;

    int tid = threadIdx.x;
    int lane = tid & 63;
    int wv = tid >> 6;
    int wgid = blockIdx.x;              // 0..639
    int xcd = wgid & 7, slot = wgid >> 3;
    int rb = xcd * 20 + (slot >> 2);
    int ct = slot & 3;
    int row0 = rb * 128;
    int col0 = ct * 80;
    int l15 = lane & 15, l4 = lane >> 4;
    int lr = lane >> 3;                 // row within 8-row chunk group
    int k8 = lane & 7;                  // k-chunk within row
    int k8x = k8 ^ lr;                  // inverse-swizzled source k-chunk

    if (BNA) {
        for (int d = tid; d < ADIM; d += 256) {
            float sc = 0.f, sh = 0.f;
            if (d < DIM) {
                const float invn = 1.0f / (float)N_NODES;
                float mean = in_s1[d] * invn;
                float var = in_s2[d] * invn - mean * mean;
                sc = bn_g[d] * rsqrtf(var + BN_EPS);
                sh = bn_be[d] - mean * sc;
            }
            s_scale[d] = sc;
            s_shift[d] = sh;
        }
        __syncthreads();
    }

    f32x4 acc[2][5];
#pragma unroll
    for (int m = 0; m < 2; ++m)
#pragma unroll
        for (int n = 0; n < 5; ++n) acc[m][n] = (f32x4){0.f, 0.f, 0.f, 0.f};

    for (int kt = 0; kt < 5; ++kt) {
        int k0 = kt * 64;
        // ---- stage A ----
        if (!BNA) {
            // async: wave wv stages chunks wv*4..wv*4+3 (rows c*8+lr)
#pragma unroll
            for (int it = 0; it < 4; ++it) {
                int c = wv * 4 + it;
                int row = c * 8 + lr;
                const ushort_t* g = A + (size_t)(row0 + row) * ADIM + k0 + k8x * 8;
                gload_lds16(g, sAc + c * 1024);
            }
        } else {
            // reg-staged with BN transform, swizzled ds_write
#pragma unroll
            for (int it = 0; it < 4; ++it) {
                int idx = tid + it * 256;
                int row = idx >> 3, kc = idx & 7;
                const ushort_t* g = A + (size_t)(row0 + row) * ADIM + k0 + kc * 8;
                union { ushort_t u[8]; uint4 v; } in, o;
                in.v = *(const uint4*)g;
                int kb = k0 + kc * 8;
#pragma unroll
                for (int j = 0; j < 8; ++j)
                    o.u[j] = f2bf(fmaxf(bf2f(in.u[j]) * s_scale[kb + j] +
                                        s_shift[kb + j], 0.0f));
                *(uint4*)(sAc + swz(row, kc)) = o.v;
            }
        }
        // ---- stage B (async): chunks wv, wv+4, wv+8 ----
        for (int c = wv; c < 10; c += 4) {
            int row = c * 8 + lr;
            const ushort_t* g = Wt + (size_t)(col0 + row) * ADIM + k0 + k8x * 8;
            gload_lds16(g, sBc + c * 1024);
        }
        __syncthreads();

#pragma unroll
        for (int kk = 0; kk < 2; ++kk) {
            bf16x8 a[2], b[5];
#pragma unroll
            for (int m = 0; m < 2; ++m)
                a[m] = *(const bf16x8*)(sAc + swz(wv * 32 + m * 16 + l15, kk * 4 + l4));
#pragma unroll
            for (int n = 0; n < 5; ++n)
                b[n] = *(const bf16x8*)(sBc + swz(n * 16 + l15, kk * 4 + l4));
#pragma unroll
            for (int m = 0; m < 2; ++m)
#pragma unroll
                for (int n = 0; n < 5; ++n)
                    acc[m][n] = __builtin_amdgcn_mfma_f32_16x16x32_bf16(
                        a[m], b[n], acc[m][n], 0, 0, 0);
        }
        __syncthreads();
    }

    // ---- write bf16 output + per-wave column stats (stats from exact f32) --
#pragma unroll
    for (int n = 0; n < 5; ++n) {
        int col = col0 + n * 16 + l15;
        float s1 = 0.f, s2 = 0.f;
#pragma unroll
        for (int m = 0; m < 2; ++m) {
#pragma unroll
            for (int r = 0; r < 4; ++r) {
                int row = row0 + wv * 32 + m * 16 + l4 * 4 + r;
                float v = acc[m][n][r];
                if (row < N_NODES && col < DIM) {
                    Ybf[(size_t)row * ADIM + col] = f2bf(v);
                    s1 += v;
                    s2 += v * v;
                }
            }
        }
        s1 += __shfl_xor(s1, 16, 64);
        s1 += __shfl_xor(s1, 32, 64);
        s2 += __shfl_xor(s2, 16, 64);
        s2 += __shfl_xor(s2, 32, 64);
        if (l4 == 0) {
            sRed[wv * 160 + n * 16 + l15] = s1;
            sRed[wv * 160 + 80 + n * 16 + l15] = s2;
        }
    }
    __syncthreads();
    if (tid < 160) {
        float v = sRed[tid] + sRed[160 + tid] + sRed[320 + tid] + sRed[480 + tid];
        int cc = (tid < 80) ? tid : tid - 80;
        int col = col0 + cc;
        if (col < DIM) atomicAdd(((tid < 80) ? gs1 : gs2) + col, v);
    }
}

// -------- pooling: sorted batch -> segmented reduction, BN2+relu inline -----
__device__ __forceinline__ int lbound(const int* __restrict__ batch, int g) {
    int lo = 0, hi = N_NODES;
    while (lo < hi) {
        int mid = (lo + hi) >> 1;
        if (batch[mid] < g) lo = mid + 1; else hi = mid;
    }
    return lo;
}

__global__ void pool_kernel(const ushort_t* __restrict__ y_bf,
                            const int* __restrict__ batch,
                            float* __restrict__ pooled,
                            float* __restrict__ counts,
                            const float* __restrict__ bs1,
                            const float* __restrict__ bs2,
                            const float* __restrict__ bg,
                            const float* __restrict__ bbe) {
    int g = blockIdx.x;
    int chunk = blockIdx.y;   // 0..3
    int d = threadIdx.x;      // 320
    int s = lbound(batch, g);
    int e = lbound(batch, g + 1);
    if (chunk == 0 && d == 0) counts[g] = (float)(e - s);
    if (d >= DIM) return;
    const float invn = 1.0f / (float)N_NODES;
    float mean = bs1[d] * invn;
    float var = bs2[d] * invn - mean * mean;
    float sc = bg[d] * rsqrtf(var + BN_EPS);
    float sh = bbe[d] - mean * sc;
    int len = e - s;
    int per = (len + 3) >> 2;
    int r0 = s + chunk * per;
    int r1 = min(r0 + per, e);
    float a = 0.f;
    for (int r = r0; r < r1; ++r)
        a += fmaxf(bf2f(y_bf[(size_t)r * ADIM + d]) * sc + sh, 0.0f);
    if (r1 > r0) atomicAdd(&pooled[(size_t)g * DIM + d], a);
}

// ---------------- MLP head ----------------
__global__ void mlp1_kernel(const float* __restrict__ pooled,
                            const float* __restrict__ counts,
                            const float* __restrict__ Wc1,
                            const float* __restrict__ bc1,
                            float* __restrict__ hidden) {
    int g = blockIdx.x;
    int j = threadIdx.x;  // 192
    if (j >= DHALF) return;
    float inv = 1.0f / fmaxf(counts[g], 1.0f);
    const float* prow = pooled + (size_t)g * DIM;
    float acc = 0.0f;
    for (int k = 0; k < DIM; ++k) acc += prow[k] * Wc1[k * DHALF + j];
    hidden[g * DHALF + j] = fmaxf(acc * inv + bc1[j], 0.0f);
}

__global__ void mlp2_kernel(const float* __restrict__ hidden,
                            const float* __restrict__ Wc2,
                            const float* __restrict__ bc2,
                            float* __restrict__ out) {
    int idx = blockIdx.x * blockDim.x + threadIdx.x;
    if (idx >= NGRAPH * NCLS) return;
    int g = idx / NCLS;
    int c = idx - g * NCLS;
    const float* hrow = hidden + g * DHALF;
    float acc = bc2[c];
    for (int j = 0; j < DHALF; ++j) acc += hrow[j] * Wc2[j * NCLS + c];
    out[idx] = acc;
}

extern "C" void kernel_launch(void* const* d_in, const int* in_sizes, int n_in,
                              void* d_out, int out_size, void* d_ws, size_t ws_size,
                              hipStream_t stream) {
    const int*   x         = (const int*)d_in[0];
    const int*   edge_index= (const int*)d_in[1];
    const float* edge_attr = (const float*)d_in[2];
    const int*   batch     = (const int*)d_in[3];
    const float* node_emb  = (const float*)d_in[4];
    const float* edge_W    = (const float*)d_in[5];
    const float* edge_b    = (const float*)d_in[6];
    const float* eps       = (const float*)d_in[7];
    const float* W1        = (const float*)d_in[8];
    const float* g1        = (const float*)d_in[10];
    const float* be1       = (const float*)d_in[11];
    const float* W2        = (const float*)d_in[12];
    const float* g2        = (const float*)d_in[14];
    const float* be2       = (const float*)d_in[15];
    const float* Wc1       = (const float*)d_in[16];
    const float* bc1       = (const float*)d_in[17];
    const float* Wc2       = (const float*)d_in[18];
    const float* bc2       = (const float*)d_in[19];
    float* out = (float*)d_out;

    const int* src = edge_index;
    const int* dst = edge_index + N_EDGES;

    char* w = (char*)d_ws;
    size_t cur_off = 0;
    auto alloc = [&](size_t bytes) {
        char* p = w + cur_off;
        cur_off += (bytes + 63) & ~(size_t)63;
        return p;
    };
    const size_t AROW = (size_t)ROWS_PAD * ADIM;
    ushort_t* h_bf  = (ushort_t*)alloc(AROW * 2);   // layer-0 input
    ushort_t* zab   = (ushort_t*)alloc(AROW * 2);   // z
    ushort_t* y1bf  = (ushort_t*)alloc(AROW * 2);   // GEMM1 output
    ushort_t* y2bf  = (ushort_t*)alloc(AROW * 2);   // GEMM2 output (pre-BN2)
    ushort_t* Wt    = (ushort_t*)alloc((size_t)10 * ADIM * ADIM * 2);
    int*      deg16 = (int*)alloc((size_t)N_NODES * NBUCK * 4);
    int*      cur16 = (int*)alloc((size_t)N_NODES * NBUCK * 4);
    int*      nodedeg = (int*)alloc((size_t)N_NODES * 4);
    int*      off   = (int*)alloc((N_NODES + 1) * 4);
    int*      psrc  = (int*)alloc((size_t)N_EDGES * 4);
    float*    pea   = (float*)alloc((size_t)N_EDGES * 8 * 4);
    float*    sbuf  = (float*)alloc((size_t)N_LAYERS * 4 * ADIM * 4); // [L][4][ADIM]
    float*    pooled= (float*)alloc((size_t)NGRAPH * DIM * 4);
    float*    counts= (float*)alloc(NGRAPH * 4);
    float*    hidden= (float*)alloc((size_t)NGRAPH * DHALF * 4);

    auto sa1 = [&](int i) { return sbuf + ((size_t)i * 4 + 0) * ADIM; };
    auto sa2 = [&](int i) { return sbuf + ((size_t)i * 4 + 1) * ADIM; };
    auto sb1 = [&](int i) { return sbuf + ((size_t)i * 4 + 2) * ADIM; };
    auto sb2 = [&](int i) { return sbuf + ((size_t)i * 4 + 3) * ADIM; };

    // ---- prep ----
    hipMemsetAsync(deg16, 0, (size_t)N_NODES * NBUCK * 4, stream);
    hipMemsetAsync(zab + (size_t)N_NODES * ADIM, 0,
                   (size_t)(ROWS_PAD - N_NODES) * ADIM * 2, stream);
    hipMemsetAsync(sbuf, 0, (size_t)N_LAYERS * 4 * ADIM * 4, stream);

    node_enc_kernel<<<CDIV(N_NODES * 40, 256), 256, 0, stream>>>(x, node_emb, h_bf);
    wt_prep_kernel<<<CDIV(10 * ADIM * ADIM, 256), 256, 0, stream>>>(W1, W2, Wt);
    deg16_kernel<<<CDIV(N_EDGES, 256), 256, 0, stream>>>(src, dst, deg16);
    nodedeg_kernel<<<CDIV(N_NODES, 256), 256, 0, stream>>>(deg16, nodedeg);
    scan_kernel<<<1, 1024, 0, stream>>>(nodedeg, off);
    cur16_kernel<<<CDIV(N_NODES, 256), 256, 0, stream>>>(deg16, off, cur16);
    scatter_kernel<<<CDIV(N_EDGES, 256), 256, 0, stream>>>(src, dst, edge_attr,
                                                           cur16, psrc, pea);

    const int GEMM_BLOCKS = (ROWS_PAD / 128) * 4;  // 640

    for (int i = 0; i < N_LAYERS; ++i) {
        // z = (1+eps)*h + agg, h = relu(BN2(y2_{i-1})) inline for i>0
        if (i == 0)
            msg_kernel<false><<<MSG_BLOCKS, 256, 0, stream>>>(
                h_bf, zab, off, psrc, pea, edge_W, edge_b, eps, i,
                nullptr, nullptr, nullptr, nullptr);
        else
            msg_kernel<true><<<MSG_BLOCKS, 256, 0, stream>>>(
                y2bf, zab, off, psrc, pea, edge_W, edge_b, eps, i,
                sb1(i - 1), sb2(i - 1), g2 + (i - 1) * DIM, be2 + (i - 1) * DIM);
        // y1 = z @ W1, stats -> sa(i)
        gemm_kernel<false><<<GEMM_BLOCKS, 256, 0, stream>>>(
            zab, Wt + (size_t)i * ADIM * ADIM, y1bf,
            nullptr, nullptr, nullptr, nullptr, sa1(i), sa2(i));
        // y2 = relu(BN1(y1)) @ W2 (BN1 fused into staging), stats -> sb(i)
        gemm_kernel<true><<<GEMM_BLOCKS, 256, 0, stream>>>(
            y1bf, Wt + (size_t)(5 + i) * ADIM * ADIM, y2bf,
            sa1(i), sa2(i), g1 + i * DIM, be1 + i * DIM, sb1(i), sb2(i));
    }

    hipMemsetAsync(pooled, 0, (size_t)NGRAPH * DIM * 4, stream);
    dim3 pgrid(NGRAPH, 4);
    pool_kernel<<<pgrid, ADIM, 0, stream>>>(y2bf, batch, pooled, counts,
                                            sb1(N_LAYERS - 1), sb2(N_LAYERS - 1),
                                            g2 + (N_LAYERS - 1) * DIM,
                                            be2 + (N_LAYERS - 1) * DIM);
    mlp1_kernel<<<NGRAPH, 192, 0, stream>>>(pooled, counts, Wc1, bc1, hidden);
    mlp2_kernel<<<CDIV(NGRAPH * NCLS, 256), 256, 0, stream>>>(hidden, Wc2, bc2, out);
}

// Round 17
// 586.710 us; speedup vs baseline: 1.3528x; 1.1093x over previous
//
#include <hip/hip_runtime.h>
#include <hip/hip_bf16.h>
#include <stdint.h>

#define N_NODES 20000
#define N_EDGES 320000
#define DIM 300
#define ADIM 320              // padded activation stride (cols 300..319 = 0)
#define ROWS_PAD 20480        // 160 * 128  (160 row-blocks = 8 XCDs x 20)
#define N_LAYERS 5
#define EDIM 7
#define NGRAPH 128
#define NCLS 6
#define DHALF 150
#define BN_EPS 1e-5f
#define NBUCK 16
#define BUCK_W 1250

#define CDIV(a, b) (((a) + (b) - 1) / (b))

typedef short bf16x8 __attribute__((ext_vector_type(8)));
typedef float f32x4 __attribute__((ext_vector_type(4)));
typedef unsigned short ushort_t;

__device__ __forceinline__ float bf2f(ushort_t u) {
    union { float f; uint32_t i; } v; v.i = ((uint32_t)u) << 16; return v.f;
}
__device__ __forceinline__ ushort_t f2bf(float f) {
    union { float f; uint32_t i; } v; v.f = f;
    uint32_t x = v.i;
    x += 0x7FFFu + ((x >> 16) & 1u);   // RTN-even (no inf/nan expected)
    return (ushort_t)(x >> 16);
}

// async global->LDS, 16B per lane; LDS dest = uniform base + lane*16
__device__ __forceinline__ void gload_lds16(const void* g, void* l) {
    __builtin_amdgcn_global_load_lds(
        (const __attribute__((address_space(1))) uint32_t*)g,
        (__attribute__((address_space(3))) uint32_t*)l, 16, 0, 0);
}

// ---------------- node encoder: h_bf[n][d] = bf16(node_emb[x[n]][d]) --------
__global__ void node_enc_kernel(const int* __restrict__ x,
                                const float* __restrict__ node_emb,
                                ushort_t* __restrict__ h_bf) {
    int idx = blockIdx.x * blockDim.x + threadIdx.x;  // 20000*40
    if (idx >= N_NODES * 40) return;
    int n = idx / 40;
    int d0 = (idx - n * 40) * 8;
    const float* src = node_emb + (size_t)x[n] * DIM;
    union { ushort_t u[8]; uint4 v; } o;
#pragma unroll
    for (int j = 0; j < 8; ++j) {
        int d = d0 + j;
        o.u[j] = (d < DIM) ? f2bf(src[d]) : (ushort_t)0;
    }
    *(uint4*)(h_bf + (size_t)n * ADIM + d0) = o.v;
}

// -------- W transpose+convert: Wt[mat][n][k] = bf16(W[k][n]), k fastest -----
__global__ void wt_prep_kernel(const float* __restrict__ W1,
                               const float* __restrict__ W2,
                               ushort_t* __restrict__ Wt) {
    int idx = blockIdx.x * blockDim.x + threadIdx.x;  // 10*320*320
    if (idx >= 10 * ADIM * ADIM) return;
    int mat = idx / (ADIM * ADIM);
    int rem = idx - mat * ADIM * ADIM;
    int n = rem / ADIM;
    int k = rem - n * ADIM;
    const float* src = (mat < 5) ? (W1 + (size_t)mat * DIM * DIM)
                                 : (W2 + (size_t)(mat - 5) * DIM * DIM);
    float v = (k < DIM && n < DIM) ? src[(size_t)k * DIM + n] : 0.0f;
    Wt[(size_t)mat * ADIM * ADIM + (size_t)n * ADIM + k] = f2bf(v);
}

// ---------------- CSR build (16-bucket src-tile counting sort) ----------------
__global__ void deg16_kernel(const int* __restrict__ src,
                             const int* __restrict__ dst,
                             int* __restrict__ deg16) {
    int e = blockIdx.x * blockDim.x + threadIdx.x;
    if (e < N_EDGES) atomicAdd(&deg16[dst[e] * NBUCK + src[e] / BUCK_W], 1);
}

__global__ void nodedeg_kernel(const int* __restrict__ deg16,
                               int* __restrict__ nodedeg) {
    int i = blockIdx.x * blockDim.x + threadIdx.x;
    if (i >= N_NODES) return;
    int tot = 0;
#pragma unroll
    for (int b = 0; b < NBUCK; ++b) tot += deg16[i * NBUCK + b];
    nodedeg[i] = tot;
}

__global__ void scan_kernel(const int* __restrict__ nodedeg,
                            int* __restrict__ off) {
    __shared__ int sh[1024];
    int t = threadIdx.x;
    int base = t * 20;
    int local[20];
    int s = 0;
#pragma unroll
    for (int j = 0; j < 20; ++j) {
        int i = base + j;
        int v = (i < N_NODES) ? nodedeg[i] : 0;
        local[j] = v;
        s += v;
    }
    sh[t] = s;
    __syncthreads();
    for (int o = 1; o < 1024; o <<= 1) {
        int v = sh[t];
        int add = (t >= o) ? sh[t - o] : 0;
        __syncthreads();
        sh[t] = v + add;
        __syncthreads();
    }
    int run = (t > 0) ? sh[t - 1] : 0;
#pragma unroll
    for (int j = 0; j < 20; ++j) {
        int i = base + j;
        if (i < N_NODES) {
            off[i] = run;
            run += local[j];
        }
    }
    if (t == 1023) off[N_NODES] = sh[1023];
}

__global__ void cur16_kernel(const int* __restrict__ deg16,
                             const int* __restrict__ off,
                             int* __restrict__ cur16) {
    int i = blockIdx.x * blockDim.x + threadIdx.x;
    if (i >= N_NODES) return;
    int c = off[i];
#pragma unroll
    for (int b = 0; b < NBUCK; ++b) {
        cur16[i * NBUCK + b] = c;
        c += deg16[i * NBUCK + b];
    }
}

__global__ void scatter_kernel(const int* __restrict__ src,
                               const int* __restrict__ dst,
                               const float* __restrict__ edge_attr,
                               int* __restrict__ cur16,
                               int* __restrict__ perm_src,
                               float* __restrict__ pea) {
    int e = blockIdx.x * blockDim.x + threadIdx.x;
    if (e >= N_EDGES) return;
    int s = src[e];
    int d = dst[e];
    int p = atomicAdd(&cur16[d * NBUCK + s / BUCK_W], 1);
    perm_src[p] = s;
    const float* ar = edge_attr + (size_t)e * EDIM;
    float* pr = pea + (size_t)p * 8;
#pragma unroll
    for (int j = 0; j < EDIM; ++j) pr[j] = ar[j];
    pr[7] = 0.0f;
}

// ------- one node per wave, 2-deep pipeline, SCALARIZED uniform values -------
// n / p0 / p1 / perm_src / pea are wave-uniform: readfirstlane forces them
// into SGPRs -> s_load on the scalar pipe, frees VALU + VGPRs.
// z = (1+eps)*h + sum relu(h[src]+ea); BNH: h = relu(BN(y_bf)) inline.
#define MSG_BLOCKS 5000
template <bool BNH>
__global__ __launch_bounds__(256) void msg_kernel(
    const ushort_t* __restrict__ hsrc, ushort_t* __restrict__ z_bf,
    const int* __restrict__ off, const int* __restrict__ perm_src,
    const float* __restrict__ pea,
    const float* __restrict__ edge_W, const float* __restrict__ edge_b,
    const float* __restrict__ eps, int layer,
    const float* __restrict__ bs1, const float* __restrict__ bs2,
    const float* __restrict__ bg, const float* __restrict__ bbe) {
    int n = __builtin_amdgcn_readfirstlane(
        (int)((blockIdx.x * 256 + threadIdx.x) >> 6));
    if (n >= N_NODES) return;
    int lane = threadIdx.x & 63;

    float ew[5][7], eb[5], sc[5], sh[5];
#pragma unroll
    for (int c = 0; c < 5; ++c) {
        int d = c * 64 + lane;
        bool ok = (d < DIM);
        eb[c] = ok ? edge_b[d] : 0.0f;
#pragma unroll
        for (int j = 0; j < EDIM; ++j)
            ew[c][j] = ok ? edge_W[j * DIM + d] : 0.0f;
        if (BNH) {
            float s = 0.f, t = 0.f;
            if (ok) {
                const float invn = 1.0f / (float)N_NODES;
                float mean = bs1[d] * invn;
                float var = bs2[d] * invn - mean * mean;
                s = bg[d] * rsqrtf(var + BN_EPS);
                t = bbe[d] - mean * s;
            }
            sc[c] = s;
            sh[c] = t;
        }
    }
    float epsv = 1.0f + eps[layer];

    int p0 = __builtin_amdgcn_readfirstlane(off[n]);
    int p1 = __builtin_amdgcn_readfirstlane(off[n + 1]);
    float acc[5] = {0.f, 0.f, 0.f, 0.f, 0.f};
    float na0, na1, na2, na3, na4, na5, na6;
    float nhv[5];
    int s2i = 0;
    if (p0 < p1) {
        int s1i = __builtin_amdgcn_readfirstlane(perm_src[p0]);
        const float* ap = pea + (size_t)p0 * 8;
        na0 = ap[0]; na1 = ap[1]; na2 = ap[2]; na3 = ap[3];
        na4 = ap[4]; na5 = ap[5]; na6 = ap[6];
        const ushort_t* hr = hsrc + (size_t)s1i * ADIM;
#pragma unroll
        for (int c = 0; c < 5; ++c) nhv[c] = bf2f(hr[c * 64 + lane]);
        if (p0 + 1 < p1) s2i = __builtin_amdgcn_readfirstlane(perm_src[p0 + 1]);
    }
    for (int p = p0; p < p1; ++p) {
        float ca0 = na0, ca1 = na1, ca2 = na2, ca3 = na3;
        float ca4 = na4, ca5 = na5, ca6 = na6;
        float chv[5];
#pragma unroll
        for (int c = 0; c < 5; ++c) chv[c] = nhv[c];
        if (p + 1 < p1) {
            const float* ap = pea + (size_t)(p + 1) * 8;
            na0 = ap[0]; na1 = ap[1]; na2 = ap[2]; na3 = ap[3];
            na4 = ap[4]; na5 = ap[5]; na6 = ap[6];
            const ushort_t* hr = hsrc + (size_t)s2i * ADIM;
#pragma unroll
            for (int c = 0; c < 5; ++c) nhv[c] = bf2f(hr[c * 64 + lane]);
            if (p + 2 < p1)
                s2i = __builtin_amdgcn_readfirstlane(perm_src[p + 2]);
        }
#pragma unroll
        for (int c = 0; c < 5; ++c) {
            float hv = BNH ? fmaxf(chv[c] * sc[c] + sh[c], 0.0f) : chv[c];
            float ea = eb[c];
            ea += ca0 * ew[c][0];
            ea += ca1 * ew[c][1];
            ea += ca2 * ew[c][2];
            ea += ca3 * ew[c][3];
            ea += ca4 * ew[c][4];
            ea += ca5 * ew[c][5];
            ea += ca6 * ew[c][6];
            acc[c] += fmaxf(hv + ea, 0.0f);
        }
    }
    const ushort_t* hn = hsrc + (size_t)n * ADIM;
    ushort_t* zr = z_bf + (size_t)n * ADIM;
#pragma unroll
    for (int c = 0; c < 5; ++c) {
        int d = c * 64 + lane;
        float hv = bf2f(hn[d]);
        if (BNH) hv = fmaxf(hv * sc[c] + sh[c], 0.0f);
        zr[d] = f2bf(epsv * hv + acc[c]);
    }
}

// ---------------- bf16 MFMA GEMM + fused BN stats ----------------------------
// 640 blocks 1D, XCD-clustered. Staging via global_load_lds (rule #21).
__device__ __forceinline__ int swz(int row, int k8) {
    return ((row << 7) + (k8 << 4)) ^ ((row & 7) << 4);
}

template <bool BNA>
__global__ __launch_bounds__(256) void gemm_kernel(
    const ushort_t* __restrict__ A, const ushort_t* __restrict__ Wt,
    ushort_t* __restrict__ Ybf,
    const float* __restrict__ in_s1, const float* __restrict__ in_s2,
    const float* __restrict__ bn_g, const float* __restrict__ bn_be,
    float* __restrict__ gs1, float* __restrict__ gs2) {
    __shared__ ushort_t sA[128 * 64];   // 16 KB (16 chunks of 1KB)
    __shared__ ushort_t sB[80 * 64];    // 10 KB (10 chunks)
    __shared__ float sRed[4 * 160];
    __shared__ float s_scale[ADIM], s_shift[ADIM];
    char* sAc = (char*)sA;
    char* sBc = (char*)sB;

    int tid = threadIdx.x;
    int lane = tid & 63;
    int wv = tid >> 6;
    int wgid = blockIdx.x;              // 0..639
    int xcd = wgid & 7, slot = wgid >> 3;
    int rb = xcd * 20 + (slot >> 2);
    int ct = slot & 3;
    int row0 = rb * 128;
    int col0 = ct * 80;
    int l15 = lane & 15, l4 = lane >> 4;
    int lr = lane >> 3;
    int k8 = lane & 7;
    int k8x = k8 ^ lr;

    if (BNA) {
        for (int d = tid; d < ADIM; d += 256) {
            float sc = 0.f, sh = 0.f;
            if (d < DIM) {
                const float invn = 1.0f / (float)N_NODES;
                float mean = in_s1[d] * invn;
                float var = in_s2[d] * invn - mean * mean;
                sc = bn_g[d] * rsqrtf(var + BN_EPS);
                sh = bn_be[d] - mean * sc;
            }
            s_scale[d] = sc;
            s_shift[d] = sh;
        }
        __syncthreads();
    }

    f32x4 acc[2][5];
#pragma unroll
    for (int m = 0; m < 2; ++m)
#pragma unroll
        for (int n = 0; n < 5; ++n) acc[m][n] = (f32x4){0.f, 0.f, 0.f, 0.f};

    for (int kt = 0; kt < 5; ++kt) {
        int k0 = kt * 64;
        if (!BNA) {
#pragma unroll
            for (int it = 0; it < 4; ++it) {
                int c = wv * 4 + it;
                int row = c * 8 + lr;
                const ushort_t* g = A + (size_t)(row0 + row) * ADIM + k0 + k8x * 8;
                gload_lds16(g, sAc + c * 1024);
            }
        } else {
#pragma unroll
            for (int it = 0; it < 4; ++it) {
                int idx = tid + it * 256;
                int row = idx >> 3, kc = idx & 7;
                const ushort_t* g = A + (size_t)(row0 + row) * ADIM + k0 + kc * 8;
                union { ushort_t u[8]; uint4 v; } in, o;
                in.v = *(const uint4*)g;
                int kb = k0 + kc * 8;
#pragma unroll
                for (int j = 0; j < 8; ++j)
                    o.u[j] = f2bf(fmaxf(bf2f(in.u[j]) * s_scale[kb + j] +
                                        s_shift[kb + j], 0.0f));
                *(uint4*)(sAc + swz(row, kc)) = o.v;
            }
        }
        for (int c = wv; c < 10; c += 4) {
            int row = c * 8 + lr;
            const ushort_t* g = Wt + (size_t)(col0 + row) * ADIM + k0 + k8x * 8;
            gload_lds16(g, sBc + c * 1024);
        }
        __syncthreads();

#pragma unroll
        for (int kk = 0; kk < 2; ++kk) {
            bf16x8 a[2], b[5];
#pragma unroll
            for (int m = 0; m < 2; ++m)
                a[m] = *(const bf16x8*)(sAc + swz(wv * 32 + m * 16 + l15, kk * 4 + l4));
#pragma unroll
            for (int n = 0; n < 5; ++n)
                b[n] = *(const bf16x8*)(sBc + swz(n * 16 + l15, kk * 4 + l4));
#pragma unroll
            for (int m = 0; m < 2; ++m)
#pragma unroll
                for (int n = 0; n < 5; ++n)
                    acc[m][n] = __builtin_amdgcn_mfma_f32_16x16x32_bf16(
                        a[m], b[n], acc[m][n], 0, 0, 0);
        }
        __syncthreads();
    }

#pragma unroll
    for (int n = 0; n < 5; ++n) {
        int col = col0 + n * 16 + l15;
        float s1 = 0.f, s2 = 0.f;
#pragma unroll
        for (int m = 0; m < 2; ++m) {
#pragma unroll
            for (int r = 0; r < 4; ++r) {
                int row = row0 + wv * 32 + m * 16 + l4 * 4 + r;
                float v = acc[m][n][r];
                if (row < N_NODES && col < DIM) {
                    Ybf[(size_t)row * ADIM + col] = f2bf(v);
                    s1 += v;
                    s2 += v * v;
                }
            }
        }
        s1 += __shfl_xor(s1, 16, 64);
        s1 += __shfl_xor(s1, 32, 64);
        s2 += __shfl_xor(s2, 16, 64);
        s2 += __shfl_xor(s2, 32, 64);
        if (l4 == 0) {
            sRed[wv * 160 + n * 16 + l15] = s1;
            sRed[wv * 160 + 80 + n * 16 + l15] = s2;
        }
    }
    __syncthreads();
    if (tid < 160) {
        float v = sRed[tid] + sRed[160 + tid] + sRed[320 + tid] + sRed[480 + tid];
        int cc = (tid < 80) ? tid : tid - 80;
        int col = col0 + cc;
        if (col < DIM) atomicAdd(((tid < 80) ? gs1 : gs2) + col, v);
    }
}

// -------- pooling: sorted batch -> segmented reduction, BN2+relu inline -----
__device__ __forceinline__ int lbound(const int* __restrict__ batch, int g) {
    int lo = 0, hi = N_NODES;
    while (lo < hi) {
        int mid = (lo + hi) >> 1;
        if (batch[mid] < g) lo = mid + 1; else hi = mid;
    }
    return lo;
}

__global__ void pool_kernel(const ushort_t* __restrict__ y_bf,
                            const int* __restrict__ batch,
                            float* __restrict__ pooled,
                            float* __restrict__ counts,
                            const float* __restrict__ bs1,
                            const float* __restrict__ bs2,
                            const float* __restrict__ bg,
                            const float* __restrict__ bbe) {
    int g = blockIdx.x;
    int chunk = blockIdx.y;   // 0..3
    int d = threadIdx.x;      // 320
    int s = lbound(batch, g);
    int e = lbound(batch, g + 1);
    if (chunk == 0 && d == 0) counts[g] = (float)(e - s);
    if (d >= DIM) return;
    const float invn = 1.0f / (float)N_NODES;
    float mean = bs1[d] * invn;
    float var = bs2[d] * invn - mean * mean;
    float sc = bg[d] * rsqrtf(var + BN_EPS);
    float sh = bbe[d] - mean * sc;
    int len = e - s;
    int per = (len + 3) >> 2;
    int r0 = s + chunk * per;
    int r1 = min(r0 + per, e);
    float a = 0.f;
    for (int r = r0; r < r1; ++r)
        a += fmaxf(bf2f(y_bf[(size_t)r * ADIM + d]) * sc + sh, 0.0f);
    if (r1 > r0) atomicAdd(&pooled[(size_t)g * DIM + d], a);
}

// ---------------- MLP head ----------------
__global__ void mlp1_kernel(const float* __restrict__ pooled,
                            const float* __restrict__ counts,
                            const float* __restrict__ Wc1,
                            const float* __restrict__ bc1,
                            float* __restrict__ hidden) {
    int g = blockIdx.x;
    int j = threadIdx.x;  // 192
    if (j >= DHALF) return;
    float inv = 1.0f / fmaxf(counts[g], 1.0f);
    const float* prow = pooled + (size_t)g * DIM;
    float acc = 0.0f;
    for (int k = 0; k < DIM; ++k) acc += prow[k] * Wc1[k * DHALF + j];
    hidden[g * DHALF + j] = fmaxf(acc * inv + bc1[j], 0.0f);
}

__global__ void mlp2_kernel(const float* __restrict__ hidden,
                            const float* __restrict__ Wc2,
                            const float* __restrict__ bc2,
                            float* __restrict__ out) {
    int idx = blockIdx.x * blockDim.x + threadIdx.x;
    if (idx >= NGRAPH * NCLS) return;
    int g = idx / NCLS;
    int c = idx - g * NCLS;
    const float* hrow = hidden + g * DHALF;
    float acc = bc2[c];
    for (int j = 0; j < DHALF; ++j) acc += hrow[j] * Wc2[j * NCLS + c];
    out[idx] = acc;
}

extern "C" void kernel_launch(void* const* d_in, const int* in_sizes, int n_in,
                              void* d_out, int out_size, void* d_ws, size_t ws_size,
                              hipStream_t stream) {
    const int*   x         = (const int*)d_in[0];
    const int*   edge_index= (const int*)d_in[1];
    const float* edge_attr = (const float*)d_in[2];
    const int*   batch     = (const int*)d_in[3];
    const float* node_emb  = (const float*)d_in[4];
    const float* edge_W    = (const float*)d_in[5];
    const float* edge_b    = (const float*)d_in[6];
    const float* eps       = (const float*)d_in[7];
    const float* W1        = (const float*)d_in[8];
    const float* g1        = (const float*)d_in[10];
    const float* be1       = (const float*)d_in[11];
    const float* W2        = (const float*)d_in[12];
    const float* g2        = (const float*)d_in[14];
    const float* be2       = (const float*)d_in[15];
    const float* Wc1       = (const float*)d_in[16];
    const float* bc1       = (const float*)d_in[17];
    const float* Wc2       = (const float*)d_in[18];
    const float* bc2       = (const float*)d_in[19];
    float* out = (float*)d_out;

    const int* src = edge_index;
    const int* dst = edge_index + N_EDGES;

    char* w = (char*)d_ws;
    size_t cur_off = 0;
    auto alloc = [&](size_t bytes) {
        char* p = w + cur_off;
        cur_off += (bytes + 63) & ~(size_t)63;
        return p;
    };
    const size_t AROW = (size_t)ROWS_PAD * ADIM;
    ushort_t* h_bf  = (ushort_t*)alloc(AROW * 2);   // layer-0 input
    ushort_t* zab   = (ushort_t*)alloc(AROW * 2);   // z
    ushort_t* y1bf  = (ushort_t*)alloc(AROW * 2);   // GEMM1 output
    ushort_t* y2bf  = (ushort_t*)alloc(AROW * 2);   // GEMM2 output (pre-BN2)
    ushort_t* Wt    = (ushort_t*)alloc((size_t)10 * ADIM * ADIM * 2);
    int*      deg16 = (int*)alloc((size_t)N_NODES * NBUCK * 4);
    int*      cur16 = (int*)alloc((size_t)N_NODES * NBUCK * 4);
    int*      nodedeg = (int*)alloc((size_t)N_NODES * 4);
    int*      off   = (int*)alloc((N_NODES + 1) * 4);
    int*      psrc  = (int*)alloc((size_t)N_EDGES * 4);
    float*    pea   = (float*)alloc((size_t)N_EDGES * 8 * 4);
    float*    sbuf  = (float*)alloc((size_t)N_LAYERS * 4 * ADIM * 4); // [L][4][ADIM]
    float*    pooled= (float*)alloc((size_t)NGRAPH * DIM * 4);
    float*    counts= (float*)alloc(NGRAPH * 4);
    float*    hidden= (float*)alloc((size_t)NGRAPH * DHALF * 4);

    auto sa1 = [&](int i) { return sbuf + ((size_t)i * 4 + 0) * ADIM; };
    auto sa2 = [&](int i) { return sbuf + ((size_t)i * 4 + 1) * ADIM; };
    auto sb1 = [&](int i) { return sbuf + ((size_t)i * 4 + 2) * ADIM; };
    auto sb2 = [&](int i) { return sbuf + ((size_t)i * 4 + 3) * ADIM; };

    // ---- prep ----
    hipMemsetAsync(deg16, 0, (size_t)N_NODES * NBUCK * 4, stream);
    hipMemsetAsync(zab + (size_t)N_NODES * ADIM, 0,
                   (size_t)(ROWS_PAD - N_NODES) * ADIM * 2, stream);
    hipMemsetAsync(sbuf, 0, (size_t)N_LAYERS * 4 * ADIM * 4, stream);

    node_enc_kernel<<<CDIV(N_NODES * 40, 256), 256, 0, stream>>>(x, node_emb, h_bf);
    wt_prep_kernel<<<CDIV(10 * ADIM * ADIM, 256), 256, 0, stream>>>(W1, W2, Wt);
    deg16_kernel<<<CDIV(N_EDGES, 256), 256, 0, stream>>>(src, dst, deg16);
    nodedeg_kernel<<<CDIV(N_NODES, 256), 256, 0, stream>>>(deg16, nodedeg);
    scan_kernel<<<1, 1024, 0, stream>>>(nodedeg, off);
    cur16_kernel<<<CDIV(N_NODES, 256), 256, 0, stream>>>(deg16, off, cur16);
    scatter_kernel<<<CDIV(N_EDGES, 256), 256, 0, stream>>>(src, dst, edge_attr,
                                                           cur16, psrc, pea);

    const int GEMM_BLOCKS = (ROWS_PAD / 128) * 4;  // 640

    for (int i = 0; i < N_LAYERS; ++i) {
        if (i == 0)
            msg_kernel<false><<<MSG_BLOCKS, 256, 0, stream>>>(
                h_bf, zab, off, psrc, pea, edge_W, edge_b, eps, i,
                nullptr, nullptr, nullptr, nullptr);
        else
            msg_kernel<true><<<MSG_BLOCKS, 256, 0, stream>>>(
                y2bf, zab, off, psrc, pea, edge_W, edge_b, eps, i,
                sb1(i - 1), sb2(i - 1), g2 + (i - 1) * DIM, be2 + (i - 1) * DIM);
        gemm_kernel<false><<<GEMM_BLOCKS, 256, 0, stream>>>(
            zab, Wt + (size_t)i * ADIM * ADIM, y1bf,
            nullptr, nullptr, nullptr, nullptr, sa1(i), sa2(i));
        gemm_kernel<true><<<GEMM_BLOCKS, 256, 0, stream>>>(
            y1bf, Wt + (size_t)(5 + i) * ADIM * ADIM, y2bf,
            sa1(i), sa2(i), g1 + i * DIM, be1 + i * DIM, sb1(i), sb2(i));
    }

    hipMemsetAsync(pooled, 0, (size_t)NGRAPH * DIM * 4, stream);
    dim3 pgrid(NGRAPH, 4);
    pool_kernel<<<pgrid, ADIM, 0, stream>>>(y2bf, batch, pooled, counts,
                                            sb1(N_LAYERS - 1), sb2(N_LAYERS - 1),
                                            g2 + (N_LAYERS - 1) * DIM,
                                            be2 + (N_LAYERS - 1) * DIM);
    mlp1_kernel<<<NGRAPH, 192, 0, stream>>>(pooled, counts, Wc1, bc1, hidden);
    mlp2_kernel<<<CDIV(NGRAPH * NCLS, 256), 256, 0, stream>>>(hidden, Wc2, bc2, out);
}

// Round 18
// 585.233 us; speedup vs baseline: 1.3562x; 1.0025x over previous
//
#include <hip/hip_runtime.h>
#include <hip/hip_bf16.h>
#include <stdint.h>

#define N_NODES 20000
#define N_EDGES 320000
#define DIM 300
#define ADIM 320              // padded activation stride (cols 300..319 = 0)
#define ROWS_PAD 20480        // 160 * 128  (160 row-blocks = 8 XCDs x 20)
#define N_LAYERS 5
#define EDIM 7
#define NGRAPH 128
#define NCLS 6
#define DHALF 150
#define BN_EPS 1e-5f
#define NBUCK 16
#define BUCK_W 1250

#define CDIV(a, b) (((a) + (b) - 1) / (b))

typedef short bf16x8 __attribute__((ext_vector_type(8)));
typedef float f32x4 __attribute__((ext_vector_type(4)));
typedef unsigned short ushort_t;

__device__ __forceinline__ float bf2f(ushort_t u) {
    union { float f; uint32_t i; } v; v.i = ((uint32_t)u) << 16; return v.f;
}
__device__ __forceinline__ ushort_t f2bf(float f) {
    union { float f; uint32_t i; } v; v.f = f;
    uint32_t x = v.i;
    x += 0x7FFFu + ((x >> 16) & 1u);   // RTN-even (no inf/nan expected)
    return (ushort_t)(x >> 16);
}

// async global->LDS, 16B per lane; LDS dest = uniform base + lane*16
__device__ __forceinline__ void gload_lds16(const void* g, void* l) {
    __builtin_amdgcn_global_load_lds(
        (const __attribute__((address_space(1))) uint32_t*)g,
        (__attribute__((address_space(3))) uint32_t*)l, 16, 0, 0);
}

// ---------------- node encoder: h_bf[n][d] = bf16(node_emb[x[n]][d]) --------
__global__ void node_enc_kernel(const int* __restrict__ x,
                                const float* __restrict__ node_emb,
                                ushort_t* __restrict__ h_bf) {
    int idx = blockIdx.x * blockDim.x + threadIdx.x;  // 20000*40
    if (idx >= N_NODES * 40) return;
    int n = idx / 40;
    int d0 = (idx - n * 40) * 8;
    const float* src = node_emb + (size_t)x[n] * DIM;
    union { ushort_t u[8]; uint4 v; } o;
#pragma unroll
    for (int j = 0; j < 8; ++j) {
        int d = d0 + j;
        o.u[j] = (d < DIM) ? f2bf(src[d]) : (ushort_t)0;
    }
    *(uint4*)(h_bf + (size_t)n * ADIM + d0) = o.v;
}

// -------- W transpose+convert: Wt[mat][n][k] = bf16(W[k][n]), k fastest -----
__global__ void wt_prep_kernel(const float* __restrict__ W1,
                               const float* __restrict__ W2,
                               ushort_t* __restrict__ Wt) {
    int idx = blockIdx.x * blockDim.x + threadIdx.x;  // 10*320*320
    if (idx >= 10 * ADIM * ADIM) return;
    int mat = idx / (ADIM * ADIM);
    int rem = idx - mat * ADIM * ADIM;
    int n = rem / ADIM;
    int k = rem - n * ADIM;
    const float* src = (mat < 5) ? (W1 + (size_t)mat * DIM * DIM)
                                 : (W2 + (size_t)(mat - 5) * DIM * DIM);
    float v = (k < DIM && n < DIM) ? src[(size_t)k * DIM + n] : 0.0f;
    Wt[(size_t)mat * ADIM * ADIM + (size_t)n * ADIM + k] = f2bf(v);
}

// ---------------- CSR build (16-bucket src-tile counting sort) ----------------
__global__ void deg16_kernel(const int* __restrict__ src,
                             const int* __restrict__ dst,
                             int* __restrict__ deg16) {
    int e = blockIdx.x * blockDim.x + threadIdx.x;
    if (e < N_EDGES) atomicAdd(&deg16[dst[e] * NBUCK + src[e] / BUCK_W], 1);
}

__global__ void nodedeg_kernel(const int* __restrict__ deg16,
                               int* __restrict__ nodedeg) {
    int i = blockIdx.x * blockDim.x + threadIdx.x;
    if (i >= N_NODES) return;
    int tot = 0;
#pragma unroll
    for (int b = 0; b < NBUCK; ++b) tot += deg16[i * NBUCK + b];
    nodedeg[i] = tot;
}

__global__ void scan_kernel(const int* __restrict__ nodedeg,
                            int* __restrict__ off) {
    __shared__ int sh[1024];
    int t = threadIdx.x;
    int base = t * 20;
    int local[20];
    int s = 0;
#pragma unroll
    for (int j = 0; j < 20; ++j) {
        int i = base + j;
        int v = (i < N_NODES) ? nodedeg[i] : 0;
        local[j] = v;
        s += v;
    }
    sh[t] = s;
    __syncthreads();
    for (int o = 1; o < 1024; o <<= 1) {
        int v = sh[t];
        int add = (t >= o) ? sh[t - o] : 0;
        __syncthreads();
        sh[t] = v + add;
        __syncthreads();
    }
    int run = (t > 0) ? sh[t - 1] : 0;
#pragma unroll
    for (int j = 0; j < 20; ++j) {
        int i = base + j;
        if (i < N_NODES) {
            off[i] = run;
            run += local[j];
        }
    }
    if (t == 1023) off[N_NODES] = sh[1023];
}

__global__ void cur16_kernel(const int* __restrict__ deg16,
                             const int* __restrict__ off,
                             int* __restrict__ cur16) {
    int i = blockIdx.x * blockDim.x + threadIdx.x;
    if (i >= N_NODES) return;
    int c = off[i];
#pragma unroll
    for (int b = 0; b < NBUCK; ++b) {
        cur16[i * NBUCK + b] = c;
        c += deg16[i * NBUCK + b];
    }
}

__global__ void scatter_kernel(const int* __restrict__ src,
                               const int* __restrict__ dst,
                               const float* __restrict__ edge_attr,
                               int* __restrict__ cur16,
                               int* __restrict__ perm_src,
                               float* __restrict__ pea) {
    int e = blockIdx.x * blockDim.x + threadIdx.x;
    if (e >= N_EDGES) return;
    int s = src[e];
    int d = dst[e];
    int p = atomicAdd(&cur16[d * NBUCK + s / BUCK_W], 1);
    perm_src[p] = s;
    const float* ar = edge_attr + (size_t)e * EDIM;
    float* pr = pea + (size_t)p * 8;
#pragma unroll
    for (int j = 0; j < EDIM; ++j) pr[j] = ar[j];
    pr[7] = 0.0f;
}

// ------- one node per wave, 2-deep pipeline, SCALARIZED uniform values -------
// n / p0 / p1 / perm_src / pea are wave-uniform: readfirstlane forces them
// into SGPRs -> s_load on the scalar pipe, frees VALU + VGPRs.
// z = (1+eps)*h + sum relu(h[src]+ea); BNH: h = relu(BN(y_bf)) inline.
#define MSG_BLOCKS 5000
template <bool BNH>
__global__ __launch_bounds__(256) void msg_kernel(
    const ushort_t* __restrict__ hsrc, ushort_t* __restrict__ z_bf,
    const int* __restrict__ off, const int* __restrict__ perm_src,
    const float* __restrict__ pea,
    const float* __restrict__ edge_W, const float* __restrict__ edge_b,
    const float* __restrict__ eps, int layer,
    const float* __restrict__ bs1, const float* __restrict__ bs2,
    const float* __restrict__ bg, const float* __restrict__ bbe) {
    int n = __builtin_amdgcn_readfirstlane(
        (int)((blockIdx.x * 256 + threadIdx.x) >> 6));
    if (n >= N_NODES) return;
    int lane = threadIdx.x & 63;

    float ew[5][7], eb[5], sc[5], sh[5];
#pragma unroll
    for (int c = 0; c < 5; ++c) {
        int d = c * 64 + lane;
        bool ok = (d < DIM);
        eb[c] = ok ? edge_b[d] : 0.0f;
#pragma unroll
        for (int j = 0; j < EDIM; ++j)
            ew[c][j] = ok ? edge_W[j * DIM + d] : 0.0f;
        if (BNH) {
            float s = 0.f, t = 0.f;
            if (ok) {
                const float invn = 1.0f / (float)N_NODES;
                float mean = bs1[d] * invn;
                float var = bs2[d] * invn - mean * mean;
                s = bg[d] * rsqrtf(var + BN_EPS);
                t = bbe[d] - mean * s;
            }
            sc[c] = s;
            sh[c] = t;
        }
    }
    float epsv = 1.0f + eps[layer];

    int p0 = __builtin_amdgcn_readfirstlane(off[n]);
    int p1 = __builtin_amdgcn_readfirstlane(off[n + 1]);
    float acc[5] = {0.f, 0.f, 0.f, 0.f, 0.f};
    float na0, na1, na2, na3, na4, na5, na6;
    float nhv[5];
    int s2i = 0;
    if (p0 < p1) {
        int s1i = __builtin_amdgcn_readfirstlane(perm_src[p0]);
        const float* ap = pea + (size_t)p0 * 8;
        na0 = ap[0]; na1 = ap[1]; na2 = ap[2]; na3 = ap[3];
        na4 = ap[4]; na5 = ap[5]; na6 = ap[6];
        const ushort_t* hr = hsrc + (size_t)s1i * ADIM;
#pragma unroll
        for (int c = 0; c < 5; ++c) nhv[c] = bf2f(hr[c * 64 + lane]);
        if (p0 + 1 < p1) s2i = __builtin_amdgcn_readfirstlane(perm_src[p0 + 1]);
    }
    for (int p = p0; p < p1; ++p) {
        float ca0 = na0, ca1 = na1, ca2 = na2, ca3 = na3;
        float ca4 = na4, ca5 = na5, ca6 = na6;
        float chv[5];
#pragma unroll
        for (int c = 0; c < 5; ++c) chv[c] = nhv[c];
        if (p + 1 < p1) {
            const float* ap = pea + (size_t)(p + 1) * 8;
            na0 = ap[0]; na1 = ap[1]; na2 = ap[2]; na3 = ap[3];
            na4 = ap[4]; na5 = ap[5]; na6 = ap[6];
            const ushort_t* hr = hsrc + (size_t)s2i * ADIM;
#pragma unroll
            for (int c = 0; c < 5; ++c) nhv[c] = bf2f(hr[c * 64 + lane]);
            if (p + 2 < p1)
                s2i = __builtin_amdgcn_readfirstlane(perm_src[p + 2]);
        }
#pragma unroll
        for (int c = 0; c < 5; ++c) {
            float hv = BNH ? fmaxf(chv[c] * sc[c] + sh[c], 0.0f) : chv[c];
            float ea = eb[c];
            ea += ca0 * ew[c][0];
            ea += ca1 * ew[c][1];
            ea += ca2 * ew[c][2];
            ea += ca3 * ew[c][3];
            ea += ca4 * ew[c][4];
            ea += ca5 * ew[c][5];
            ea += ca6 * ew[c][6];
            acc[c] += fmaxf(hv + ea, 0.0f);
        }
    }
    const ushort_t* hn = hsrc + (size_t)n * ADIM;
    ushort_t* zr = z_bf + (size_t)n * ADIM;
#pragma unroll
    for (int c = 0; c < 5; ++c) {
        int d = c * 64 + lane;
        float hv = bf2f(hn[d]);
        if (BNH) hv = fmaxf(hv * sc[c] + sh[c], 0.0f);
        zr[d] = f2bf(epsv * hv + acc[c]);
    }
}

// ---------------- bf16 MFMA GEMM + fused BN stats ----------------------------
// 640 blocks 1D, XCD-clustered. Staging via global_load_lds (rule #21).
__device__ __forceinline__ int swz(int row, int k8) {
    return ((row << 7) + (k8 << 4)) ^ ((row & 7) << 4);
}

template <bool BNA>
__global__ __launch_bounds__(256) void gemm_kernel(
    const ushort_t* __restrict__ A, const ushort_t* __restrict__ Wt,
    ushort_t* __restrict__ Ybf,
    const float* __restrict__ in_s1, const float* __restrict__ in_s2,
    const float* __restrict__ bn_g, const float* __restrict__ bn_be,
    float* __restrict__ gs1, float* __restrict__ gs2) {
    __shared__ ushort_t sA[128 * 64];   // 16 KB (16 chunks of 1KB)
    __shared__ ushort_t sB[80 * 64];    // 10 KB (10 chunks)
    __shared__ float sRed[4 * 160];
    __shared__ float s_scale[ADIM], s_shift[ADIM];
    char* sAc = (char*)sA;
    char* sBc = (char*)sB;

    int tid = threadIdx.x;
    int lane = tid & 63;
    int wv = tid >> 6;
    int wgid = blockIdx.x;              // 0..639
    int xcd = wgid & 7, slot = wgid >> 3;
    int rb = xcd * 20 + (slot >> 2);
    int ct = slot & 3;
    int row0 = rb * 128;
    int col0 = ct * 80;
    int l15 = lane & 15, l4 = lane >> 4;
    int lr = lane >> 3;
    int k8 = lane & 7;
    int k8x = k8 ^ lr;

    if (BNA) {
        for (int d = tid; d < ADIM; d += 256) {
            float sc = 0.f, sh = 0.f;
            if (d < DIM) {
                const float invn = 1.0f / (float)N_NODES;
                float mean = in_s1[d] * invn;
                float var = in_s2[d] * invn - mean * mean;
                sc = bn_g[d] * rsqrtf(var + BN_EPS);
                sh = bn_be[d] - mean * sc;
            }
            s_scale[d] = sc;
            s_shift[d] = sh;
        }
        __syncthreads();
    }

    f32x4 acc[2][5];
#pragma unroll
    for (int m = 0; m < 2; ++m)
#pragma unroll
        for (int n = 0; n < 5; ++n) acc[m][n] = (f32x4){0.f, 0.f, 0.f, 0.f};

    for (int kt = 0; kt < 5; ++kt) {
        int k0 = kt * 64;
        if (!BNA) {
#pragma unroll
            for (int it = 0; it < 4; ++it) {
                int c = wv * 4 + it;
                int row = c * 8 + lr;
                const ushort_t* g = A + (size_t)(row0 + row) * ADIM + k0 + k8x * 8;
                gload_lds16(g, sAc + c * 1024);
            }
        } else {
#pragma unroll
            for (int it = 0; it < 4; ++it) {
                int idx = tid + it * 256;
                int row = idx >> 3, kc = idx & 7;
                const ushort_t* g = A + (size_t)(row0 + row) * ADIM + k0 + kc * 8;
                union { ushort_t u[8]; uint4 v; } in, o;
                in.v = *(const uint4*)g;
                int kb = k0 + kc * 8;
#pragma unroll
                for (int j = 0; j < 8; ++j)
                    o.u[j] = f2bf(fmaxf(bf2f(in.u[j]) * s_scale[kb + j] +
                                        s_shift[kb + j], 0.0f));
                *(uint4*)(sAc + swz(row, kc)) = o.v;
            }
        }
        for (int c = wv; c < 10; c += 4) {
            int row = c * 8 + lr;
            const ushort_t* g = Wt + (size_t)(col0 + row) * ADIM + k0 + k8x * 8;
            gload_lds16(g, sBc + c * 1024);
        }
        __syncthreads();

#pragma unroll
        for (int kk = 0; kk < 2; ++kk) {
            bf16x8 a[2], b[5];
#pragma unroll
            for (int m = 0; m < 2; ++m)
                a[m] = *(const bf16x8*)(sAc + swz(wv * 32 + m * 16 + l15, kk * 4 + l4));
#pragma unroll
            for (int n = 0; n < 5; ++n)
                b[n] = *(const bf16x8*)(sBc + swz(n * 16 + l15, kk * 4 + l4));
#pragma unroll
            for (int m = 0; m < 2; ++m)
#pragma unroll
                for (int n = 0; n < 5; ++n)
                    acc[m][n] = __builtin_amdgcn_mfma_f32_16x16x32_bf16(
                        a[m], b[n], acc[m][n], 0, 0, 0);
        }
        __syncthreads();
    }

#pragma unroll
    for (int n = 0; n < 5; ++n) {
        int col = col0 + n * 16 + l15;
        float s1 = 0.f, s2 = 0.f;
#pragma unroll
        for (int m = 0; m < 2; ++m) {
#pragma unroll
            for (int r = 0; r < 4; ++r) {
                int row = row0 + wv * 32 + m * 16 + l4 * 4 + r;
                float v = acc[m][n][r];
                if (row < N_NODES && col < DIM) {
                    Ybf[(size_t)row * ADIM + col] = f2bf(v);
                    s1 += v;
                    s2 += v * v;
                }
            }
        }
        s1 += __shfl_xor(s1, 16, 64);
        s1 += __shfl_xor(s1, 32, 64);
        s2 += __shfl_xor(s2, 16, 64);
        s2 += __shfl_xor(s2, 32, 64);
        if (l4 == 0) {
            sRed[wv * 160 + n * 16 + l15] = s1;
            sRed[wv * 160 + 80 + n * 16 + l15] = s2;
        }
    }
    __syncthreads();
    if (tid < 160) {
        float v = sRed[tid] + sRed[160 + tid] + sRed[320 + tid] + sRed[480 + tid];
        int cc = (tid < 80) ? tid : tid - 80;
        int col = col0 + cc;
        if (col < DIM) atomicAdd(((tid < 80) ? gs1 : gs2) + col, v);
    }
}

// -------- pooling: sorted batch -> segmented reduction, BN2+relu inline -----
__device__ __forceinline__ int lbound(const int* __restrict__ batch, int g) {
    int lo = 0, hi = N_NODES;
    while (lo < hi) {
        int mid = (lo + hi) >> 1;
        if (batch[mid] < g) lo = mid + 1; else hi = mid;
    }
    return lo;
}

__global__ void pool_kernel(const ushort_t* __restrict__ y_bf,
                            const int* __restrict__ batch,
                            float* __restrict__ pooled,
                            float* __restrict__ counts,
                            const float* __restrict__ bs1,
                            const float* __restrict__ bs2,
                            const float* __restrict__ bg,
                            const float* __restrict__ bbe) {
    int g = blockIdx.x;
    int chunk = blockIdx.y;   // 0..3
    int d = threadIdx.x;      // 320
    int s = lbound(batch, g);
    int e = lbound(batch, g + 1);
    if (chunk == 0 && d == 0) counts[g] = (float)(e - s);
    if (d >= DIM) return;
    const float invn = 1.0f / (float)N_NODES;
    float mean = bs1[d] * invn;
    float var = bs2[d] * invn - mean * mean;
    float sc = bg[d] * rsqrtf(var + BN_EPS);
    float sh = bbe[d] - mean * sc;
    int len = e - s;
    int per = (len + 3) >> 2;
    int r0 = s + chunk * per;
    int r1 = min(r0 + per, e);
    float a = 0.f;
    for (int r = r0; r < r1; ++r)
        a += fmaxf(bf2f(y_bf[(size_t)r * ADIM + d]) * sc + sh, 0.0f);
    if (r1 > r0) atomicAdd(&pooled[(size_t)g * DIM + d], a);
}

// ---------------- MLP head ----------------
__global__ void mlp1_kernel(const float* __restrict__ pooled,
                            const float* __restrict__ counts,
                            const float* __restrict__ Wc1,
                            const float* __restrict__ bc1,
                            float* __restrict__ hidden) {
    int g = blockIdx.x;
    int j = threadIdx.x;  // 192
    if (j >= DHALF) return;
    float inv = 1.0f / fmaxf(counts[g], 1.0f);
    const float* prow = pooled + (size_t)g * DIM;
    float acc = 0.0f;
    for (int k = 0; k < DIM; ++k) acc += prow[k] * Wc1[k * DHALF + j];
    hidden[g * DHALF + j] = fmaxf(acc * inv + bc1[j], 0.0f);
}

__global__ void mlp2_kernel(const float* __restrict__ hidden,
                            const float* __restrict__ Wc2,
                            const float* __restrict__ bc2,
                            float* __restrict__ out) {
    int idx = blockIdx.x * blockDim.x + threadIdx.x;
    if (idx >= NGRAPH * NCLS) return;
    int g = idx / NCLS;
    int c = idx - g * NCLS;
    const float* hrow = hidden + g * DHALF;
    float acc = bc2[c];
    for (int j = 0; j < DHALF; ++j) acc += hrow[j] * Wc2[j * NCLS + c];
    out[idx] = acc;
}

extern "C" void kernel_launch(void* const* d_in, const int* in_sizes, int n_in,
                              void* d_out, int out_size, void* d_ws, size_t ws_size,
                              hipStream_t stream) {
    const int*   x         = (const int*)d_in[0];
    const int*   edge_index= (const int*)d_in[1];
    const float* edge_attr = (const float*)d_in[2];
    const int*   batch     = (const int*)d_in[3];
    const float* node_emb  = (const float*)d_in[4];
    const float* edge_W    = (const float*)d_in[5];
    const float* edge_b    = (const float*)d_in[6];
    const float* eps       = (const float*)d_in[7];
    const float* W1        = (const float*)d_in[8];
    const float* g1        = (const float*)d_in[10];
    const float* be1       = (const float*)d_in[11];
    const float* W2        = (const float*)d_in[12];
    const float* g2        = (const float*)d_in[14];
    const float* be2       = (const float*)d_in[15];
    const float* Wc1       = (const float*)d_in[16];
    const float* bc1       = (const float*)d_in[17];
    const float* Wc2       = (const float*)d_in[18];
    const float* bc2       = (const float*)d_in[19];
    float* out = (float*)d_out;

    const int* src = edge_index;
    const int* dst = edge_index + N_EDGES;

    char* w = (char*)d_ws;
    size_t cur_off = 0;
    auto alloc = [&](size_t bytes) {
        char* p = w + cur_off;
        cur_off += (bytes + 63) & ~(size_t)63;
        return p;
    };
    const size_t AROW = (size_t)ROWS_PAD * ADIM;
    ushort_t* h_bf  = (ushort_t*)alloc(AROW * 2);   // layer-0 input
    ushort_t* zab   = (ushort_t*)alloc(AROW * 2);   // z
    ushort_t* y1bf  = (ushort_t*)alloc(AROW * 2);   // GEMM1 output
    ushort_t* y2bf  = (ushort_t*)alloc(AROW * 2);   // GEMM2 output (pre-BN2)
    ushort_t* Wt    = (ushort_t*)alloc((size_t)10 * ADIM * ADIM * 2);
    int*      deg16 = (int*)alloc((size_t)N_NODES * NBUCK * 4);
    int*      cur16 = (int*)alloc((size_t)N_NODES * NBUCK * 4);
    int*      nodedeg = (int*)alloc((size_t)N_NODES * 4);
    int*      off   = (int*)alloc((N_NODES + 1) * 4);
    int*      psrc  = (int*)alloc((size_t)N_EDGES * 4);
    float*    pea   = (float*)alloc((size_t)N_EDGES * 8 * 4);
    float*    sbuf  = (float*)alloc((size_t)N_LAYERS * 4 * ADIM * 4); // [L][4][ADIM]
    float*    pooled= (float*)alloc((size_t)NGRAPH * DIM * 4);
    float*    counts= (float*)alloc(NGRAPH * 4);
    float*    hidden= (float*)alloc((size_t)NGRAPH * DHALF * 4);

    auto sa1 = [&](int i) { return sbuf + ((size_t)i * 4 + 0) * ADIM; };
    auto sa2 = [&](int i) { return sbuf + ((size_t)i * 4 + 1) * ADIM; };
    auto sb1 = [&](int i) { return sbuf + ((size_t)i * 4 + 2) * ADIM; };
    auto sb2 = [&](int i) { return sbuf + ((size_t)i * 4 + 3) * ADIM; };

    // ---- prep ----
    hipMemsetAsync(deg16, 0, (size_t)N_NODES * NBUCK * 4, stream);
    hipMemsetAsync(zab + (size_t)N_NODES * ADIM, 0,
                   (size_t)(ROWS_PAD - N_NODES) * ADIM * 2, stream);
    hipMemsetAsync(sbuf, 0, (size_t)N_LAYERS * 4 * ADIM * 4, stream);

    node_enc_kernel<<<CDIV(N_NODES * 40, 256), 256, 0, stream>>>(x, node_emb, h_bf);
    wt_prep_kernel<<<CDIV(10 * ADIM * ADIM, 256), 256, 0, stream>>>(W1, W2, Wt);
    deg16_kernel<<<CDIV(N_EDGES, 256), 256, 0, stream>>>(src, dst, deg16);
    nodedeg_kernel<<<CDIV(N_NODES, 256), 256, 0, stream>>>(deg16, nodedeg);
    scan_kernel<<<1, 1024, 0, stream>>>(nodedeg, off);
    cur16_kernel<<<CDIV(N_NODES, 256), 256, 0, stream>>>(deg16, off, cur16);
    scatter_kernel<<<CDIV(N_EDGES, 256), 256, 0, stream>>>(src, dst, edge_attr,
                                                           cur16, psrc, pea);

    const int GEMM_BLOCKS = (ROWS_PAD / 128) * 4;  // 640

    for (int i = 0; i < N_LAYERS; ++i) {
        if (i == 0)
            msg_kernel<false><<<MSG_BLOCKS, 256, 0, stream>>>(
                h_bf, zab, off, psrc, pea, edge_W, edge_b, eps, i,
                nullptr, nullptr, nullptr, nullptr);
        else
            msg_kernel<true><<<MSG_BLOCKS, 256, 0, stream>>>(
                y2bf, zab, off, psrc, pea, edge_W, edge_b, eps, i,
                sb1(i - 1), sb2(i - 1), g2 + (i - 1) * DIM, be2 + (i - 1) * DIM);
        gemm_kernel<false><<<GEMM_BLOCKS, 256, 0, stream>>>(
            zab, Wt + (size_t)i * ADIM * ADIM, y1bf,
            nullptr, nullptr, nullptr, nullptr, sa1(i), sa2(i));
        gemm_kernel<true><<<GEMM_BLOCKS, 256, 0, stream>>>(
            y1bf, Wt + (size_t)(5 + i) * ADIM * ADIM, y2bf,
            sa1(i), sa2(i), g1 + i * DIM, be1 + i * DIM, sb1(i), sb2(i));
    }

    hipMemsetAsync(pooled, 0, (size_t)NGRAPH * DIM * 4, stream);
    dim3 pgrid(NGRAPH, 4);
    pool_kernel<<<pgrid, ADIM, 0, stream>>>(y2bf, batch, pooled, counts,
                                            sb1(N_LAYERS - 1), sb2(N_LAYERS - 1),
                                            g2 + (N_LAYERS - 1) * DIM,
                                            be2 + (N_LAYERS - 1) * DIM);
    mlp1_kernel<<<NGRAPH, 192, 0, stream>>>(pooled, counts, Wc1, bc1, hidden);
    mlp2_kernel<<<CDIV(NGRAPH * NCLS, 256), 256, 0, stream>>>(hidden, Wc2, bc2, out);
}